// Round 1
// baseline (924.529 us; speedup 1.0000x reference)
//
#include <hip/hip_runtime.h>
#include <math.h>

// Problem constants: N=4, H=W=64, C=256, G=8, GC=32, K=3, P=9, pad=1
// Padded sample image: 66x66.

// ---------------- transpose NCHW -> NHWC ----------------
__global__ __launch_bounds__(256) void k_tr(const float* __restrict__ x, float* __restrict__ xs){
  __shared__ float tile[32][33];
  int n = blockIdx.z;
  int hw0 = blockIdx.x*32, c0 = blockIdx.y*32;
  int tx = threadIdx.x, ty = threadIdx.y; // (32,8)
  #pragma unroll
  for (int ii=0; ii<4; ii++){
    int ci = ty + ii*8;
    tile[ci][tx] = x[(size_t)(n*256 + c0+ci)*4096 + hw0 + tx];
  }
  __syncthreads();
  #pragma unroll
  for (int ii=0; ii<4; ii++){
    int hwi = ty + ii*8;
    xs[((size_t)n*4096 + hw0+hwi)*256 + c0 + tx] = tile[tx][hwi];
  }
}

// ---------------- generic tiled GEMM: C = A @ B + bias ----------------
// A: M x K row-major; B: K x Nn row-major; C row stride ldc (or padded write)
__global__ __launch_bounds__(256) void k_gemm(
    const float* __restrict__ A, const float* __restrict__ B,
    const float* __restrict__ bias, float* __restrict__ Cmat,
    int M, int K, int Nn, int ldc, int padout)
{
  __shared__ float As[16][64];
  __shared__ float Bs[16][68];
  int tid = threadIdx.x;
  int m0 = blockIdx.x*64, n0 = blockIdx.y*64;
  int ty = tid>>4, tx = tid&15;
  int lr = tid>>2, lq = tid&3;
  int wr = tid>>4, wc = tid&15;
  float acc[4][4] = {};
  for (int k0=0; k0<K; k0+=16){
    float4 av = *(const float4*)(A + (size_t)(m0+lr)*K + k0 + lq*4);
    As[lq*4+0][lr]=av.x; As[lq*4+1][lr]=av.y; As[lq*4+2][lr]=av.z; As[lq*4+3][lr]=av.w;
    int bc = n0 + wc*4;
    float4 bv;
    if (bc + 3 < Nn) {
      bv = *(const float4*)(B + (size_t)(k0+wr)*Nn + bc);
    } else {
      bv.x = (bc+0<Nn)? B[(size_t)(k0+wr)*Nn + bc+0] : 0.f;
      bv.y = (bc+1<Nn)? B[(size_t)(k0+wr)*Nn + bc+1] : 0.f;
      bv.z = (bc+2<Nn)? B[(size_t)(k0+wr)*Nn + bc+2] : 0.f;
      bv.w = (bc+3<Nn)? B[(size_t)(k0+wr)*Nn + bc+3] : 0.f;
    }
    *(float4*)&Bs[wr][wc*4] = bv;
    __syncthreads();
    #pragma unroll
    for (int kk=0; kk<16; kk++){
      float a[4], b[4];
      #pragma unroll
      for (int i=0;i<4;i++) a[i] = As[kk][ty*4+i];
      #pragma unroll
      for (int j=0;j<4;j++) b[j] = Bs[kk][tx*4+j];
      #pragma unroll
      for (int i=0;i<4;i++)
        #pragma unroll
        for (int j=0;j<4;j++)
          acc[i][j] += a[i]*b[j];
    }
    __syncthreads();
  }
  #pragma unroll
  for (int i=0;i<4;i++){
    int row = m0 + ty*4 + i;
    #pragma unroll
    for (int j=0;j<4;j++){
      int col = n0 + tx*4 + j;
      if (col < Nn){
        float v = acc[i][j] + bias[col];
        if (padout){
          int nn = row>>12, hw = row&4095, h = hw>>6, w = hw&63;
          Cmat[((size_t)((nn*66)+(h+1))*66 + (w+1))*256 + col] = v;
        } else {
          Cmat[(size_t)row*ldc + col] = v;
        }
      }
    }
  }
}

// ---------------- implicit-GEMM 3x3 conv (NHWC, HWIO weights) ----------------
// In: (4,64,64,256). Out: (4,Hout,Wout,256). stride 1 or 2, pad 1.
__global__ __launch_bounds__(256) void k_conv(
    const float* __restrict__ In, const float* __restrict__ Wt,
    const float* __restrict__ bias, float* __restrict__ Out,
    int stride, int wshift)
{
  __shared__ float As[16][64];
  __shared__ float Bs[16][68];
  int tid = threadIdx.x;
  int m0 = blockIdx.x*64, n0 = blockIdx.y*64;
  int ty = tid>>4, tx = tid&15;
  int lr = tid>>2, lq = tid&3;
  int wr = tid>>4, wc = tid&15;
  int m = m0 + lr;
  int hwmask = (1<<(2*wshift)) - 1;
  int wmask = (1<<wshift) - 1;
  int nb = m >> (2*wshift);
  int rem = m & hwmask;
  int ho = rem >> wshift;
  int wo = rem & wmask;
  float acc[4][4] = {};
  for (int kh=0; kh<3; kh++){
    int hin = ho*stride + kh - 1;
    for (int kw=0; kw<3; kw++){
      int win = wo*stride + kw - 1;
      bool valid = (hin>=0) && (hin<64) && (win>=0) && (win<64);
      const float* aptr = In + ((size_t)((nb*64+hin)*64+win))*256 + lq*4;
      const float* wptr = Wt + ((size_t)(kh*3+kw)*256)*256 + n0 + wc*4;
      for (int kc=0; kc<256; kc+=16){
        float4 av = valid ? *(const float4*)(aptr + kc) : make_float4(0.f,0.f,0.f,0.f);
        As[lq*4+0][lr]=av.x; As[lq*4+1][lr]=av.y; As[lq*4+2][lr]=av.z; As[lq*4+3][lr]=av.w;
        float4 bv = *(const float4*)(wptr + (size_t)(kc+wr)*256);
        *(float4*)&Bs[wr][wc*4] = bv;
        __syncthreads();
        #pragma unroll
        for (int kk=0; kk<16; kk++){
          float a[4], b[4];
          #pragma unroll
          for (int i=0;i<4;i++) a[i] = As[kk][ty*4+i];
          #pragma unroll
          for (int j=0;j<4;j++) b[j] = Bs[kk][tx*4+j];
          #pragma unroll
          for (int i=0;i<4;i++)
            #pragma unroll
            for (int j=0;j<4;j++)
              acc[i][j] += a[i]*b[j];
        }
        __syncthreads();
      }
    }
  }
  #pragma unroll
  for (int i=0;i<4;i++){
    int row = m0 + ty*4 + i;
    #pragma unroll
    for (int j=0;j<4;j++){
      int col = n0 + tx*4 + j;
      Out[(size_t)row*256 + col] = acc[i][j] + bias[col];
    }
  }
}

// ---------------- depthwise conv 3x3 + LayerNorm + exact GELU ----------------
__global__ __launch_bounds__(256) void k_dwln(
    const float* __restrict__ xs, const float* __restrict__ dw_w, const float* __restrict__ dw_b,
    const float* __restrict__ ln_g, const float* __restrict__ ln_b, float* __restrict__ t)
{
  int pos = blockIdx.x;
  int c = threadIdx.x;
  int nb = pos>>12, hw = pos&4095, h = hw>>6, w = hw&63;
  float v = dw_b[c];
  #pragma unroll
  for (int kh=0; kh<3; kh++){
    int hin = h + kh - 1;
    if (hin < 0 || hin >= 64) continue;
    #pragma unroll
    for (int kw=0; kw<3; kw++){
      int win = w + kw - 1;
      if (win < 0 || win >= 64) continue;
      v += xs[((size_t)((nb*64+hin)*64+win))*256 + c] * dw_w[(kh*3+kw)*256 + c];
    }
  }
  // LayerNorm over 256 channels (biased var)
  float s = v, s2 = v*v;
  #pragma unroll
  for (int msk=1; msk<64; msk<<=1){ s += __shfl_xor(s, msk); s2 += __shfl_xor(s2, msk); }
  __shared__ float red[8];
  int wave = threadIdx.x>>6;
  if ((threadIdx.x&63)==0){ red[wave]=s; red[4+wave]=s2; }
  __syncthreads();
  float S = red[0]+red[1]+red[2]+red[3];
  float S2 = red[4]+red[5]+red[6]+red[7];
  float mu = S*(1.f/256.f);
  float var = S2*(1.f/256.f) - mu*mu;
  float xn = (v-mu)*rsqrtf(var+1e-5f)*ln_g[c] + ln_b[c];
  float ge = 0.5f*xn*(1.f + erff(xn*0.70710678118654752f));
  t[(size_t)pos*256 + c] = ge;
}

// ---------------- softmax over P=9 per (pos, g) ----------------
__global__ __launch_bounds__(256) void k_softmax(float* __restrict__ D){
  int idx = blockIdx.x*256 + threadIdx.x;   // 16384*8 total
  float* p = D + (size_t)(idx>>3)*216 + 144 + (idx&7)*9;
  float mx = p[0];
  #pragma unroll
  for (int i=1;i<9;i++) mx = fmaxf(mx, p[i]);
  float e[9]; float s = 0.f;
  #pragma unroll
  for (int i=0;i<9;i++){ e[i] = expf(p[i]-mx); s += e[i]; }
  float r = 1.f/s;
  #pragma unroll
  for (int i=0;i<9;i++) p[i] = e[i]*r;
}

// ---------------- DCNv3 bilinear sampling + mask aggregation ----------------
// xp: (4,66,66,256) padded x_proj; D: (16384, 216) [144 offsets | 72 softmaxed mask]
__global__ __launch_bounds__(256) void k_sample(
    const float* __restrict__ xp, const float* __restrict__ D, float* __restrict__ y)
{
  int pos = blockIdx.x;
  int g = threadIdx.x>>5, c = threadIdx.x&31;
  int nb = pos>>12, hw = pos&4095, h = hw>>6, w = hw&63;
  const float* off = D + (size_t)pos*216 + g*18;
  const float* msk = D + (size_t)pos*216 + 144 + g*9;
  const float* img = xp + (size_t)nb*4356*256 + g*32 + c;
  float acc = 0.f;
  #pragma unroll
  for (int p=0;p<9;p++){
    int di = p/3 - 1, dj = p%3 - 1;     // grid x uses d[i]=p/3, grid y uses d[j]=p%3
    float px = (float)(w + 1 + di) + off[p*2+0];
    float py = (float)(h + 1 + dj) + off[p*2+1];
    float x0f = floorf(px), y0f = floorf(py);
    float wx1 = px - x0f, wy1 = py - y0f;
    int x0 = (int)x0f, y0 = (int)y0f;
    float sv = 0.f;
    #pragma unroll
    for (int cy=0; cy<2; cy++){
      int yi = y0+cy;
      if (yi < 0 || yi >= 66) continue;
      float wy = cy ? wy1 : 1.f-wy1;
      #pragma unroll
      for (int cx=0; cx<2; cx++){
        int xi = x0+cx;
        if (xi < 0 || xi >= 66) continue;
        float wx = cx ? wx1 : 1.f-wx1;
        sv += img[((size_t)(yi*66+xi))*256] * (wx*wy);
      }
    }
    acc += sv * msk[p];
  }
  y[(size_t)pos*256 + g*32 + c] = acc;
}

// ---------------- GroupNorm(32) stats: block per (n, group) ----------------
__global__ __launch_bounds__(256) void k_gnstats(const float* __restrict__ X, float* __restrict__ stats, int npos){
  int nb = blockIdx.x>>5, grp = blockIdx.x&31;
  int cc = threadIdx.x&7, pl = threadIdx.x>>3;
  float s=0.f, s2=0.f;
  for (int p=pl; p<npos; p+=32){
    float v = X[((size_t)nb*npos + p)*256 + grp*8 + cc];
    s += v; s2 += v*v;
  }
  #pragma unroll
  for (int msk=1; msk<64; msk<<=1){ s += __shfl_xor(s, msk); s2 += __shfl_xor(s2, msk); }
  __shared__ float red[8];
  int wave = threadIdx.x>>6;
  if ((threadIdx.x&63)==0){ red[wave]=s; red[4+wave]=s2; }
  __syncthreads();
  if (threadIdx.x==0){
    float S = red[0]+red[1]+red[2]+red[3];
    float S2 = red[4]+red[5]+red[6]+red[7];
    float cnt = (float)(npos*8);
    float mu = S/cnt;
    float var = S2/cnt - mu*mu;
    stats[blockIdx.x*2+0] = mu;
    stats[blockIdx.x*2+1] = rsqrtf(var + 1e-5f);
  }
}

// ---------------- GroupNorm apply (+SiLU) (+final NCHW transpose) ----------------
__global__ __launch_bounds__(256) void k_gnapply(
    const float* __restrict__ X, const float* __restrict__ stats,
    const float* __restrict__ gamma, const float* __restrict__ beta,
    float* __restrict__ O, int nposshift, int do_silu, int to_nchw)
{
  int idx = blockIdx.x*256 + threadIdx.x;
  int c = idx & 255;
  int row = idx >> 8;
  int nb = row >> nposshift;
  int p = row & ((1<<nposshift)-1);
  int grp = c >> 3;
  float mu = stats[(nb*32+grp)*2+0];
  float rs = stats[(nb*32+grp)*2+1];
  float v = (X[idx] - mu) * rs * gamma[c] + beta[c];
  if (do_silu) v = v / (1.f + expf(-v));
  if (to_nchw) O[((size_t)(nb*256 + c) << nposshift) + p] = v;
  else O[idx] = v;
}

extern "C" void kernel_launch(void* const* d_in, const int* in_sizes, int n_in,
                              void* d_out, int out_size, void* d_ws, size_t ws_size,
                              hipStream_t stream) {
  const float* x      = (const float*)d_in[0];
  const float* w_in   = (const float*)d_in[1];
  const float* b_in   = (const float*)d_in[2];
  const float* dw_w   = (const float*)d_in[3];
  const float* dw_b   = (const float*)d_in[4];
  const float* ln_g   = (const float*)d_in[5];
  const float* ln_b   = (const float*)d_in[6];
  const float* w_off  = (const float*)d_in[7];
  const float* b_off  = (const float*)d_in[8];
  const float* w_mask = (const float*)d_in[9];
  const float* b_mask = (const float*)d_in[10];
  const float* w_out  = (const float*)d_in[11];
  const float* b_out  = (const float*)d_in[12];
  const float* gn1_g  = (const float*)d_in[13];
  const float* gn1_b  = (const float*)d_in[14];
  const float* conv1_w= (const float*)d_in[15];
  const float* conv1_b= (const float*)d_in[16];
  const float* gn2_g  = (const float*)d_in[17];
  const float* gn2_b  = (const float*)d_in[18];
  const float* down_w = (const float*)d_in[19];
  const float* down_b = (const float*)d_in[20];
  const float* gn3_g  = (const float*)d_in[21];
  const float* gn3_b  = (const float*)d_in[22];
  float* out = (float*)d_out;

  float* wsf  = (float*)d_ws;
  float* bufA = wsf;                 // 4*64*64*256   = 4,194,304 floats (xs / y1 / conv1-out)
  float* bufB = bufA + 4194304;      // 4*66*66*256   = 4,460,544 floats (xp / down-out)
  float* bufC = bufB + 4460544;      // 4,194,304 floats (t / y2 / gn-out)
  float* bufD = bufC + 4194304;      // 16384*216     = 3,538,944 floats (offsets+mask)
  float* stats = bufD + 3538944;     // 256 floats

  // 1. NCHW -> NHWC
  k_tr<<<dim3(128,8,4), dim3(32,8), 0, stream>>>(x, bufA);
  // 2. input_proj -> padded xp (borders zero)
  hipMemsetAsync(bufB, 0, (size_t)4460544*4, stream);
  k_gemm<<<dim3(256,4), 256, 0, stream>>>(bufA, w_in, b_in, bufB, 16384, 256, 256, 256, 1);
  // 3. depthwise conv + LN + GELU -> t
  k_dwln<<<dim3(16384), 256, 0, stream>>>(bufA, dw_w, dw_b, ln_g, ln_b, bufC);
  // 4. offset / mask GEMMs + softmax
  k_gemm<<<dim3(256,3), 256, 0, stream>>>(bufC, w_off, b_off, bufD, 16384, 256, 144, 216, 0);
  k_gemm<<<dim3(256,2), 256, 0, stream>>>(bufC, w_mask, b_mask, bufD+144, 16384, 256, 72, 216, 0);
  k_softmax<<<dim3(512), 256, 0, stream>>>(bufD);
  // 5. bilinear sample + aggregate -> bufA
  k_sample<<<dim3(16384), 256, 0, stream>>>(bufB, bufD, bufA);
  // 6. output_proj -> bufC
  k_gemm<<<dim3(256,4), 256, 0, stream>>>(bufA, w_out, b_out, bufC, 16384, 256, 256, 256, 0);
  // 7. GN1 + SiLU (in-place bufC)
  k_gnstats<<<dim3(128), 256, 0, stream>>>(bufC, stats, 4096);
  k_gnapply<<<dim3(16384), 256, 0, stream>>>(bufC, stats, gn1_g, gn1_b, bufC, 12, 1, 0);
  // 8. conv1 -> bufA
  k_conv<<<dim3(256,4), 256, 0, stream>>>(bufC, conv1_w, conv1_b, bufA, 1, 6);
  // 9. GN2 + SiLU (in-place bufA)
  k_gnstats<<<dim3(128), 256, 0, stream>>>(bufA, stats, 4096);
  k_gnapply<<<dim3(16384), 256, 0, stream>>>(bufA, stats, gn2_g, gn2_b, bufA, 12, 1, 0);
  // 10. down conv (stride 2) -> bufB
  k_conv<<<dim3(64,4), 256, 0, stream>>>(bufA, down_w, down_b, bufB, 2, 5);
  // 11. GN3 (no act) -> out, NCHW
  k_gnstats<<<dim3(128), 256, 0, stream>>>(bufB, stats, 1024);
  k_gnapply<<<dim3(4096), 256, 0, stream>>>(bufB, stats, gn3_g, gn3_b, out, 10, 0, 1);
}

// Round 2
// 480.499 us; speedup vs baseline: 1.9241x; 1.9241x over previous
//
#include <hip/hip_runtime.h>
#include <hip/hip_bf16.h>
#include <math.h>

// N=4, H=W=64, C=256, G=8, GC=32, K=3, P=9, pad=1. Padded spatial: 66x66.

typedef __attribute__((ext_vector_type(8))) short bf16x8;
typedef __attribute__((ext_vector_type(4))) float f32x4;

__device__ __forceinline__ void gload16(const void* g, void* l){
  auto gp = reinterpret_cast<const __attribute__((address_space(1))) uint32_t*>(
      reinterpret_cast<uintptr_t>(g));
  auto lp = reinterpret_cast<__attribute__((address_space(3))) uint32_t*>(
      reinterpret_cast<uintptr_t>(l));
  __builtin_amdgcn_global_load_lds(gp, lp, 16, 0, 0);
}

// ---------------- NCHW fp32 -> NHWC bf16 ----------------
__global__ __launch_bounds__(256) void k_tr(const float* __restrict__ x, __hip_bfloat16* __restrict__ xs){
  __shared__ float tile[32][33];
  int n = blockIdx.z;
  int hw0 = blockIdx.x*32, c0 = blockIdx.y*32;
  int tx = threadIdx.x, ty = threadIdx.y; // (32,8)
  #pragma unroll
  for (int ii=0; ii<4; ii++){
    int ci = ty + ii*8;
    tile[ci][tx] = x[(size_t)(n*256 + c0+ci)*4096 + hw0 + tx];
  }
  __syncthreads();
  #pragma unroll
  for (int ii=0; ii<4; ii++){
    int hwi = ty + ii*8;
    xs[((size_t)n*4096 + hw0+hwi)*256 + c0 + tx] = __float2bfloat16(tile[tx][hwi]);
  }
}

// ---------------- weight transpose fp32 [Kd][256] -> bf16 [256][Kd] ----------------
__global__ __launch_bounds__(256) void k_wtrans(const float* __restrict__ W, __hip_bfloat16* __restrict__ WT, int Kd){
  __shared__ float tl[32][257];
  int k0 = blockIdx.x*32;
  #pragma unroll
  for (int dk=0; dk<32; dk++) tl[dk][threadIdx.x] = W[(size_t)(k0+dk)*256 + threadIdx.x];
  __syncthreads();
  #pragma unroll
  for (int r=0; r<32; r++){
    int co = r*8 + (threadIdx.x>>5);
    int dk = threadIdx.x&31;
    WT[(size_t)co*Kd + k0 + dk] = __float2bfloat16(tl[dk][co]);
  }
}

// ---------------- combined offset+mask weight: WT [256][256], rows 0..143 off, 144..215 mask, rest 0 ----
__global__ __launch_bounds__(256) void k_womT(const float* __restrict__ w_off, const float* __restrict__ w_mask,
                       const float* __restrict__ b_off, const float* __restrict__ b_mask,
                       __hip_bfloat16* __restrict__ WT, float* __restrict__ bias){
  int n = blockIdx.x, k = threadIdx.x;
  float v = (n<144) ? w_off[(size_t)k*144 + n] : (n<216 ? w_mask[(size_t)k*72 + (n-144)] : 0.f);
  WT[(size_t)n*256 + k] = __float2bfloat16(v);
  if (k==0) bias[n] = (n<144) ? b_off[n] : (n<216 ? b_mask[n-144] : 0.f);
}

// ---------------- MFMA GEMM / implicit conv ----------------
// AMODE 0: A = [M][KTOT] bf16.  AMODE 1: A = padded (4,66,66,256) bf16, implicit 3x3 im2col, stride STRIDE.
// OMODE 0: fp32 [M][256]+bias. OMODE 1: bf16 padded (4,66,66,256)+bias. OMODE 2: fp32 ldc=216, col<216, +bias.
template<int AMODE, int OMODE, int STRIDE, int KTOT>
__global__ __launch_bounds__(256) void k_mm(
    const __hip_bfloat16* __restrict__ A, const __hip_bfloat16* __restrict__ Bt,
    const float* __restrict__ bias, float* __restrict__ OF, __hip_bfloat16* __restrict__ OH)
{
  __shared__ uint4 lds4[4096];           // 64 KB: [buf:2][A 16K | B 16K]
  char* ldsc = (char*)lds4;
  const int tid = threadIdx.x;
  const int lane = tid & 63;
  const int wv = tid >> 6;
  const int wr = wv >> 1, wc = wv & 1;
  const int m0 = blockIdx.x * 128, n0 = blockIdx.y * 128;

  // ---- staging constants: flat = j*256+tid; row=flat>>3; swizzled source byte
  const int cpr = (tid & 7) << 4;             // c' byte within 128B row (linear LDS dest)
  const int swz_s = ((tid >> 3) & 7) << 4;
  const int cby = cpr ^ swz_s;                // source byte within row (involution)
  const int kl = cby >> 1;                    // element offset 0..63
  int aoff[4], boff[4];
  #pragma unroll
  for (int j=0;j<4;j++){
    int row = j*32 + (tid>>3);
    if (AMODE==0){
      aoff[j] = (m0 + row) * KTOT + kl;
    } else {
      int m = m0 + row;
      int n, ho, wo;
      if (STRIDE==1){ n = m>>12; ho = (m>>6)&63; wo = m&63; }
      else          { n = m>>10; ho = (m>>5)&31; wo = m&31; }
      aoff[j] = ((n*66 + ho*STRIDE)*66 + wo*STRIDE)*256 + kl;
    }
    boff[j] = (n0 + row) * KTOT + kl;
  }
  char* ldsst = ldsc + wv*1024;  // wave-uniform dest base (+buf*32768 +j*4096; B at +16384)

  // ---- compute constants
  const int fr = lane & 15;
  const int kb = (lane >> 4) << 4;
  const int swz_r = (fr & 7) << 4;
  int aRow[4], bRow[4];
  #pragma unroll
  for (int i=0;i<4;i++){
    aRow[i] = (wr*64 + i*16 + fr) * 128;
    bRow[i] = 16384 + (wc*64 + i*16 + fr) * 128;
  }
  int cb[2];
  cb[0] = kb ^ swz_r;
  cb[1] = (64 | kb) ^ swz_r;

  f32x4 acc[4][4];
  #pragma unroll
  for (int mi=0;mi<4;mi++)
    #pragma unroll
    for (int ni=0;ni<4;ni++)
      acc[mi][ni] = (f32x4){0.f,0.f,0.f,0.f};

  auto STAGE = [&](int buf, int t){
    const int k0 = t*64;
    int astep;
    if (AMODE==1){
      int tap = k0 >> 8;
      int kh = (tap>=6) ? 2 : (tap>=3 ? 1 : 0);
      int kw = tap - kh*3;
      astep = (kh*66 + kw)*256 + (k0 & 255);
    } else astep = k0;
    char* db = ldsst + buf*32768;
    #pragma unroll
    for (int j=0;j<4;j++){
      gload16(A + aoff[j] + astep, db + j*4096);
      gload16(Bt + boff[j] + k0, db + 16384 + j*4096);
    }
  };

  constexpr int NT = KTOT / 64;
  STAGE(0, 0);
  __syncthreads();
  for (int t=0; t<NT; ++t){
    if (t+1 < NT) STAGE((t+1)&1, t+1);
    char* cbase = ldsc + (t&1)*32768;
    #pragma unroll
    for (int kk=0; kk<2; kk++){
      bf16x8 av[4], bv[4];
      #pragma unroll
      for (int i=0;i<4;i++) av[i] = *(const bf16x8*)(cbase + aRow[i] + cb[kk]);
      #pragma unroll
      for (int i=0;i<4;i++) bv[i] = *(const bf16x8*)(cbase + bRow[i] + cb[kk]);
      #pragma unroll
      for (int mi=0;mi<4;mi++)
        #pragma unroll
        for (int ni=0;ni<4;ni++)
          acc[mi][ni] = __builtin_amdgcn_mfma_f32_16x16x32_bf16(av[mi], bv[ni], acc[mi][ni], 0,0,0);
    }
    __syncthreads();
  }

  // ---- epilogue: D col = lane&15, row = (lane>>4)*4 + r
  float bn[4];
  #pragma unroll
  for (int ni=0;ni<4;ni++) bn[ni] = bias[n0 + wc*64 + ni*16 + fr];
  #pragma unroll
  for (int mi=0;mi<4;mi++){
    #pragma unroll
    for (int r=0;r<4;r++){
      int gr = m0 + wr*64 + mi*16 + (lane>>4)*4 + r;
      #pragma unroll
      for (int ni=0;ni<4;ni++){
        int gc = n0 + wc*64 + ni*16 + fr;
        float v = acc[mi][ni][r] + bn[ni];
        if (OMODE==0){
          OF[(size_t)gr*256 + gc] = v;
        } else if (OMODE==1){
          int n = gr>>12, h = (gr>>6)&63, w = gr&63;
          OH[((size_t)((n*66)+(h+1))*66 + (w+1))*256 + gc] = __float2bfloat16(v);
        } else {
          if (gc < 216) OF[(size_t)gr*216 + gc] = v;
        }
      }
    }
  }
}

// ---------------- depthwise conv 3x3 + LayerNorm + exact GELU (bf16 in/out) ----------------
__global__ __launch_bounds__(256) void k_dwln(
    const __hip_bfloat16* __restrict__ xs, const float* __restrict__ dw_w, const float* __restrict__ dw_b,
    const float* __restrict__ ln_g, const float* __restrict__ ln_b, __hip_bfloat16* __restrict__ t)
{
  int pos = blockIdx.x;
  int c = threadIdx.x;
  int nb = pos>>12, hw = pos&4095, h = hw>>6, w = hw&63;
  float v = dw_b[c];
  #pragma unroll
  for (int kh=0; kh<3; kh++){
    int hin = h + kh - 1;
    if (hin < 0 || hin >= 64) continue;
    #pragma unroll
    for (int kw=0; kw<3; kw++){
      int win = w + kw - 1;
      if (win < 0 || win >= 64) continue;
      v += __bfloat162float(xs[((size_t)((nb*64+hin)*64+win))*256 + c]) * dw_w[(kh*3+kw)*256 + c];
    }
  }
  float s = v, s2 = v*v;
  #pragma unroll
  for (int msk=1; msk<64; msk<<=1){ s += __shfl_xor(s, msk); s2 += __shfl_xor(s2, msk); }
  __shared__ float red[8];
  int wave = threadIdx.x>>6;
  if ((threadIdx.x&63)==0){ red[wave]=s; red[4+wave]=s2; }
  __syncthreads();
  float S = red[0]+red[1]+red[2]+red[3];
  float S2 = red[4]+red[5]+red[6]+red[7];
  float mu = S*(1.f/256.f);
  float var = S2*(1.f/256.f) - mu*mu;
  float xn = (v-mu)*rsqrtf(var+1e-5f)*ln_g[c] + ln_b[c];
  float ge = 0.5f*xn*(1.f + erff(xn*0.70710678118654752f));
  t[(size_t)pos*256 + c] = __float2bfloat16(ge);
}

// ---------------- softmax over P=9 per (pos, g) ----------------
__global__ __launch_bounds__(256) void k_softmax(float* __restrict__ D){
  int idx = blockIdx.x*256 + threadIdx.x;
  float* p = D + (size_t)(idx>>3)*216 + 144 + (idx&7)*9;
  float mx = p[0];
  #pragma unroll
  for (int i=1;i<9;i++) mx = fmaxf(mx, p[i]);
  float e[9]; float s = 0.f;
  #pragma unroll
  for (int i=0;i<9;i++){ e[i] = expf(p[i]-mx); s += e[i]; }
  float r = 1.f/s;
  #pragma unroll
  for (int i=0;i<9;i++) p[i] = e[i]*r;
}

// ---------------- DCNv3 bilinear sampling + mask aggregation ----------------
__global__ __launch_bounds__(256) void k_sample(
    const __hip_bfloat16* __restrict__ xp, const float* __restrict__ D, __hip_bfloat16* __restrict__ y)
{
  int pos = blockIdx.x;
  int g = threadIdx.x>>5, c = threadIdx.x&31;
  int nb = pos>>12, hw = pos&4095, h = hw>>6, w = hw&63;
  const float* off = D + (size_t)pos*216 + g*18;
  const float* msk = D + (size_t)pos*216 + 144 + g*9;
  const __hip_bfloat16* img = xp + (size_t)nb*4356*256 + g*32 + c;
  float acc = 0.f;
  #pragma unroll
  for (int p=0;p<9;p++){
    int di = p/3 - 1, dj = p%3 - 1;
    float px = (float)(w + 1 + di) + off[p*2+0];
    float py = (float)(h + 1 + dj) + off[p*2+1];
    float x0f = floorf(px), y0f = floorf(py);
    float wx1 = px - x0f, wy1 = py - y0f;
    int x0 = (int)x0f, y0 = (int)y0f;
    float sv = 0.f;
    #pragma unroll
    for (int cy=0; cy<2; cy++){
      int yi = y0+cy;
      if (yi < 0 || yi >= 66) continue;
      float wy = cy ? wy1 : 1.f-wy1;
      #pragma unroll
      for (int cx=0; cx<2; cx++){
        int xi = x0+cx;
        if (xi < 0 || xi >= 66) continue;
        float wx = cx ? wx1 : 1.f-wx1;
        sv += __bfloat162float(img[((size_t)(yi*66+xi))*256]) * (wx*wy);
      }
    }
    acc += sv * msk[p];
  }
  y[(size_t)pos*256 + g*32 + c] = __float2bfloat16(acc);
}

// ---------------- GroupNorm(32) stats ----------------
__global__ __launch_bounds__(256) void k_gnstats(const float* __restrict__ X, float* __restrict__ stats, int npos){
  int nb = blockIdx.x>>5, grp = blockIdx.x&31;
  int cc = threadIdx.x&7, pl = threadIdx.x>>3;
  float s=0.f, s2=0.f;
  for (int p=pl; p<npos; p+=32){
    float v = X[((size_t)nb*npos + p)*256 + grp*8 + cc];
    s += v; s2 += v*v;
  }
  #pragma unroll
  for (int msk=1; msk<64; msk<<=1){ s += __shfl_xor(s, msk); s2 += __shfl_xor(s2, msk); }
  __shared__ float red[8];
  int wave = threadIdx.x>>6;
  if ((threadIdx.x&63)==0){ red[wave]=s; red[4+wave]=s2; }
  __syncthreads();
  if (threadIdx.x==0){
    float S = red[0]+red[1]+red[2]+red[3];
    float S2 = red[4]+red[5]+red[6]+red[7];
    float cnt = (float)(npos*8);
    float mu = S/cnt;
    float var = S2/cnt - mu*mu;
    stats[blockIdx.x*2+0] = mu;
    stats[blockIdx.x*2+1] = rsqrtf(var + 1e-5f);
  }
}

// ---------------- GroupNorm apply: outmode 1 = SiLU + padded bf16 (66x66); 2 = fp32 NCHW ----------------
__global__ __launch_bounds__(256) void k_gnapply(
    const float* __restrict__ X, const float* __restrict__ stats,
    const float* __restrict__ gamma, const float* __restrict__ beta,
    float* __restrict__ OF, __hip_bfloat16* __restrict__ OH,
    int nposshift, int do_silu, int outmode)
{
  int idx = blockIdx.x*256 + threadIdx.x;
  int c = idx & 255;
  int row = idx >> 8;
  int nb = row >> nposshift;
  int p = row & ((1<<nposshift)-1);
  int grp = c >> 3;
  float mu = stats[(nb*32+grp)*2+0];
  float rs = stats[(nb*32+grp)*2+1];
  float v = (X[idx] - mu) * rs * gamma[c] + beta[c];
  if (do_silu) v = v / (1.f + expf(-v));
  if (outmode == 1){
    int h = (row>>6)&63, w = row&63;
    OH[((size_t)((nb*66)+(h+1))*66 + (w+1))*256 + c] = __float2bfloat16(v);
  } else {
    OF[((size_t)(nb*256 + c) << nposshift) + p] = v;
  }
}

extern "C" void kernel_launch(void* const* d_in, const int* in_sizes, int n_in,
                              void* d_out, int out_size, void* d_ws, size_t ws_size,
                              hipStream_t stream) {
  const float* x      = (const float*)d_in[0];
  const float* w_in   = (const float*)d_in[1];
  const float* b_in   = (const float*)d_in[2];
  const float* dw_w   = (const float*)d_in[3];
  const float* dw_b   = (const float*)d_in[4];
  const float* ln_g   = (const float*)d_in[5];
  const float* ln_b   = (const float*)d_in[6];
  const float* w_off  = (const float*)d_in[7];
  const float* b_off  = (const float*)d_in[8];
  const float* w_mask = (const float*)d_in[9];
  const float* b_mask = (const float*)d_in[10];
  const float* w_out  = (const float*)d_in[11];
  const float* b_out  = (const float*)d_in[12];
  const float* gn1_g  = (const float*)d_in[13];
  const float* gn1_b  = (const float*)d_in[14];
  const float* conv1_w= (const float*)d_in[15];
  const float* conv1_b= (const float*)d_in[16];
  const float* gn2_g  = (const float*)d_in[17];
  const float* gn2_b  = (const float*)d_in[18];
  const float* down_w = (const float*)d_in[19];
  const float* down_b = (const float*)d_in[20];
  const float* gn3_g  = (const float*)d_in[21];
  const float* gn3_b  = (const float*)d_in[22];
  float* out = (float*)d_out;

  char* wsb = (char*)d_ws;
  float* R0 = (float*)wsb;                              // 16 MB fp32 (y2 / downout)
  float* R1 = (float*)(wsb + 16777216);                 // 16 MB fp32 (bufD / conv1out)
  __hip_bfloat16* R2 = (__hip_bfloat16*)(wsb + 33554432); // 8 MB bf16 (xs -> agg)
  __hip_bfloat16* R3 = (__hip_bfloat16*)(wsb + 41943040); // 8.92 MB bf16 (xp -> gn2pad)
  __hip_bfloat16* R4 = (__hip_bfloat16*)(wsb + 50864128); // 8.92 MB bf16 (t -> gn1pad)
  char* R5 = wsb + 59785216;
  __hip_bfloat16* w_inT  = (__hip_bfloat16*)R5;
  __hip_bfloat16* w_outT = (__hip_bfloat16*)(R5 + 131072);
  __hip_bfloat16* w_omT  = (__hip_bfloat16*)(R5 + 262144);
  __hip_bfloat16* c1T    = (__hip_bfloat16*)(R5 + 393216);
  __hip_bfloat16* dnT    = (__hip_bfloat16*)(R5 + 1572864);
  float* bias_om         = (float*)(R5 + 2752512);
  float* stats           = (float*)(R5 + 2753536);

  // weight prep
  k_wtrans<<<8, 256, 0, stream>>>(w_in, w_inT, 256);
  k_wtrans<<<8, 256, 0, stream>>>(w_out, w_outT, 256);
  k_wtrans<<<72, 256, 0, stream>>>(conv1_w, c1T, 2304);
  k_wtrans<<<72, 256, 0, stream>>>(down_w, dnT, 2304);
  k_womT<<<256, 256, 0, stream>>>(w_off, w_mask, b_off, b_mask, w_omT, bias_om);

  // 1. NCHW -> NHWC bf16
  k_tr<<<dim3(128,8,4), dim3(32,8), 0, stream>>>(x, R2);
  // 2. input_proj -> padded bf16 xp
  hipMemsetAsync(R3, 0, 8921088, stream);
  k_mm<0,1,1,256><<<dim3(128,2), 256, 0, stream>>>(R2, w_inT, b_in, nullptr, R3);
  // 3. depthwise conv + LN + GELU -> t
  k_dwln<<<16384, 256, 0, stream>>>(R2, dw_w, dw_b, ln_g, ln_b, R4);
  // 4. fused offset+mask GEMM + softmax
  k_mm<0,2,1,256><<<dim3(128,2), 256, 0, stream>>>(R4, w_omT, bias_om, R1, nullptr);
  k_softmax<<<512, 256, 0, stream>>>(R1);
  // 5. sample -> agg (reuse R2; xs dead)
  k_sample<<<16384, 256, 0, stream>>>(R3, R1, R2);
  // 6. output_proj -> y2 fp32
  k_mm<0,0,1,256><<<dim3(128,2), 256, 0, stream>>>(R2, w_outT, b_out, R0, nullptr);
  // 7. GN1 + SiLU -> padded bf16 (R4; t dead)
  k_gnstats<<<128, 256, 0, stream>>>(R0, stats, 4096);
  hipMemsetAsync(R4, 0, 8921088, stream);
  k_gnapply<<<16384, 256, 0, stream>>>(R0, stats, gn1_g, gn1_b, nullptr, R4, 12, 1, 1);
  // 8. conv1 (implicit GEMM) -> R1 fp32 (bufD dead)
  k_mm<1,0,1,2304><<<dim3(128,2), 256, 0, stream>>>(R4, c1T, conv1_b, R1, nullptr);
  // 9. GN2 + SiLU -> padded bf16 (R3; xp dead)
  k_gnstats<<<128, 256, 0, stream>>>(R1, stats, 4096);
  hipMemsetAsync(R3, 0, 8921088, stream);
  k_gnapply<<<16384, 256, 0, stream>>>(R1, stats, gn2_g, gn2_b, nullptr, R3, 12, 1, 1);
  // 10. down conv stride 2 -> R0 fp32 (y2 dead)
  k_mm<1,0,2,2304><<<dim3(32,2), 256, 0, stream>>>(R3, dnT, down_b, R0, nullptr);
  // 11. GN3 -> out NCHW fp32
  k_gnstats<<<128, 256, 0, stream>>>(R0, stats, 1024);
  k_gnapply<<<4096, 256, 0, stream>>>(R0, stats, gn3_g, gn3_b, out, nullptr, 10, 0, 2);
}

// Round 3
// 317.063 us; speedup vs baseline: 2.9159x; 1.5155x over previous
//
#include <hip/hip_runtime.h>
#include <hip/hip_bf16.h>
#include <math.h>

// N=4, H=W=64, C=256, G=8, GC=32, K=3, P=9, pad=1. Padded spatial: 66x66.

typedef __attribute__((ext_vector_type(8))) short bf16x8;
typedef __attribute__((ext_vector_type(4))) float f32x4;

__device__ __forceinline__ float bf2f(unsigned short u){
  union { unsigned int i; float f; } v; v.i = ((unsigned int)u)<<16; return v.f;
}
__device__ __forceinline__ unsigned short f2b(float f){
  __hip_bfloat16 h = __float2bfloat16(f);
  return *reinterpret_cast<unsigned short*>(&h);
}

__device__ __forceinline__ void gload16(const void* g, void* l){
  auto gp = reinterpret_cast<const __attribute__((address_space(1))) uint32_t*>(
      reinterpret_cast<uintptr_t>(g));
  auto lp = reinterpret_cast<__attribute__((address_space(3))) uint32_t*>(
      reinterpret_cast<uintptr_t>(l));
  __builtin_amdgcn_global_load_lds(gp, lp, 16, 0, 0);
}

// ---------------- NCHW fp32 -> NHWC bf16 ----------------
__global__ __launch_bounds__(256) void k_tr(const float* __restrict__ x, __hip_bfloat16* __restrict__ xs){
  __shared__ float tile[32][33];
  int n = blockIdx.z;
  int hw0 = blockIdx.x*32, c0 = blockIdx.y*32;
  int tx = threadIdx.x, ty = threadIdx.y; // (32,8)
  #pragma unroll
  for (int ii=0; ii<4; ii++){
    int ci = ty + ii*8;
    tile[ci][tx] = x[(size_t)(n*256 + c0+ci)*4096 + hw0 + tx];
  }
  __syncthreads();
  #pragma unroll
  for (int ii=0; ii<4; ii++){
    int hwi = ty + ii*8;
    xs[((size_t)n*4096 + hw0+hwi)*256 + c0 + tx] = __float2bfloat16(tile[tx][hwi]);
  }
}

// ---------------- weight transpose fp32 [Kd][256] -> bf16 [256][Kd] ----------------
__global__ __launch_bounds__(256) void k_wtrans(const float* __restrict__ W, __hip_bfloat16* __restrict__ WT, int Kd){
  __shared__ float tl[32][257];
  int k0 = blockIdx.x*32;
  #pragma unroll
  for (int dk=0; dk<32; dk++) tl[dk][threadIdx.x] = W[(size_t)(k0+dk)*256 + threadIdx.x];
  __syncthreads();
  #pragma unroll
  for (int r=0; r<32; r++){
    int co = r*8 + (threadIdx.x>>5);
    int dk = threadIdx.x&31;
    WT[(size_t)co*Kd + k0 + dk] = __float2bfloat16(tl[dk][co]);
  }
}

// ---------------- combined offset+mask weight ----------------
__global__ __launch_bounds__(256) void k_womT(const float* __restrict__ w_off, const float* __restrict__ w_mask,
                       const float* __restrict__ b_off, const float* __restrict__ b_mask,
                       __hip_bfloat16* __restrict__ WT, float* __restrict__ bias){
  int n = blockIdx.x, k = threadIdx.x;
  float v = (n<144) ? w_off[(size_t)k*144 + n] : (n<216 ? w_mask[(size_t)k*72 + (n-144)] : 0.f);
  WT[(size_t)n*256 + k] = __float2bfloat16(v);
  if (k==0) bias[n] = (n<144) ? b_off[n] : (n<216 ? b_mask[n-144] : 0.f);
}

// ---------------- zero the border cells of a (4,66,66,256) bf16 buffer ----------------
__global__ __launch_bounds__(256) void k_border(__hip_bfloat16* __restrict__ buf){
  int gid = blockIdx.x*8 + (threadIdx.x>>5);
  if (gid >= 1040) return;
  int n = gid/260; int ci = gid - n*260;
  int r, c;
  if (ci < 66){ r = 0; c = ci; }
  else if (ci < 132){ r = 65; c = ci-66; }
  else { int q = ci-132; r = 1 + (q>>1); c = (q&1) ? 65 : 0; }
  uint4* p = (uint4*)(buf + ((size_t)((n*66+r)*66+c))*256) + (threadIdx.x&31);
  *p = make_uint4(0,0,0,0);
}

// ---------------- MFMA GEMM / implicit conv ----------------
template<int AMODE, int OMODE, int STRIDE, int KTOT>
__global__ __launch_bounds__(256) void k_mm(
    const __hip_bfloat16* __restrict__ A, const __hip_bfloat16* __restrict__ Bt,
    const float* __restrict__ bias, float* __restrict__ OF, __hip_bfloat16* __restrict__ OH)
{
  __shared__ uint4 lds4[4096];           // 64 KB: [buf:2][A 16K | B 16K]
  char* ldsc = (char*)lds4;
  const int tid = threadIdx.x;
  const int lane = tid & 63;
  const int wv = tid >> 6;
  const int wr = wv >> 1, wc = wv & 1;
  const int m0 = blockIdx.x * 128, n0 = blockIdx.y * 128;

  const int cpr = (tid & 7) << 4;
  const int swz_s = ((tid >> 3) & 7) << 4;
  const int cby = cpr ^ swz_s;
  const int kl = cby >> 1;
  int aoff[4], boff[4];
  #pragma unroll
  for (int j=0;j<4;j++){
    int row = j*32 + (tid>>3);
    if (AMODE==0){
      aoff[j] = (m0 + row) * KTOT + kl;
    } else {
      int m = m0 + row;
      int n, ho, wo;
      if (STRIDE==1){ n = m>>12; ho = (m>>6)&63; wo = m&63; }
      else          { n = m>>10; ho = (m>>5)&31; wo = m&31; }
      aoff[j] = ((n*66 + ho*STRIDE)*66 + wo*STRIDE)*256 + kl;
    }
    boff[j] = (n0 + row) * KTOT + kl;
  }
  char* ldsst = ldsc + wv*1024;

  const int fr = lane & 15;
  const int kb = (lane >> 4) << 4;
  const int swz_r = (fr & 7) << 4;
  int aRow[4], bRow[4];
  #pragma unroll
  for (int i=0;i<4;i++){
    aRow[i] = (wr*64 + i*16 + fr) * 128;
    bRow[i] = 16384 + (wc*64 + i*16 + fr) * 128;
  }
  int cb[2];
  cb[0] = kb ^ swz_r;
  cb[1] = (64 | kb) ^ swz_r;

  f32x4 acc[4][4];
  #pragma unroll
  for (int mi=0;mi<4;mi++)
    #pragma unroll
    for (int ni=0;ni<4;ni++)
      acc[mi][ni] = (f32x4){0.f,0.f,0.f,0.f};

  auto STAGE = [&](int buf, int t){
    const int k0 = t*64;
    int astep;
    if (AMODE==1){
      int tap = k0 >> 8;
      int kh = (tap>=6) ? 2 : (tap>=3 ? 1 : 0);
      int kw = tap - kh*3;
      astep = (kh*66 + kw)*256 + (k0 & 255);
    } else astep = k0;
    char* db = ldsst + buf*32768;
    #pragma unroll
    for (int j=0;j<4;j++){
      gload16(A + aoff[j] + astep, db + j*4096);
      gload16(Bt + boff[j] + k0, db + 16384 + j*4096);
    }
  };

  constexpr int NT = KTOT / 64;
  STAGE(0, 0);
  __syncthreads();
  for (int t=0; t<NT; ++t){
    if (t+1 < NT) STAGE((t+1)&1, t+1);
    char* cbase = ldsc + (t&1)*32768;
    #pragma unroll
    for (int kk=0; kk<2; kk++){
      bf16x8 av[4], bv[4];
      #pragma unroll
      for (int i=0;i<4;i++) av[i] = *(const bf16x8*)(cbase + aRow[i] + cb[kk]);
      #pragma unroll
      for (int i=0;i<4;i++) bv[i] = *(const bf16x8*)(cbase + bRow[i] + cb[kk]);
      #pragma unroll
      for (int mi=0;mi<4;mi++)
        #pragma unroll
        for (int ni=0;ni<4;ni++)
          acc[mi][ni] = __builtin_amdgcn_mfma_f32_16x16x32_bf16(av[mi], bv[ni], acc[mi][ni], 0,0,0);
    }
    __syncthreads();
  }

  float bn[4];
  #pragma unroll
  for (int ni=0;ni<4;ni++) bn[ni] = bias[n0 + wc*64 + ni*16 + fr];
  #pragma unroll
  for (int mi=0;mi<4;mi++){
    #pragma unroll
    for (int r=0;r<4;r++){
      int gr = m0 + wr*64 + mi*16 + (lane>>4)*4 + r;
      #pragma unroll
      for (int ni=0;ni<4;ni++){
        int gc = n0 + wc*64 + ni*16 + fr;
        float v = acc[mi][ni][r] + bn[ni];
        if (OMODE==0){
          OF[(size_t)gr*256 + gc] = v;
        } else if (OMODE==1){
          int n = gr>>12, h = (gr>>6)&63, w = gr&63;
          OH[((size_t)((n*66)+(h+1))*66 + (w+1))*256 + gc] = __float2bfloat16(v);
        } else {
          if (gc < 216) OF[(size_t)gr*216 + gc] = v;
        }
      }
    }
  }
}

// ---------------- depthwise conv 3x3 + LayerNorm + GELU, vectorized 8ch/thread ----------------
__global__ __launch_bounds__(256) void k_dwln(
    const __hip_bfloat16* __restrict__ xs, const float* __restrict__ dw_w, const float* __restrict__ dw_b,
    const float* __restrict__ ln_g, const float* __restrict__ ln_b, __hip_bfloat16* __restrict__ t)
{
  __shared__ float lw[9*256];
  __shared__ float lb[256], lg[256], lbt[256];
  int tid = threadIdx.x;
  #pragma unroll
  for (int p=0;p<9;p++) lw[p*256+tid] = dw_w[p*256+tid];
  lb[tid] = dw_b[tid]; lg[tid] = ln_g[tid]; lbt[tid] = ln_b[tid];
  __syncthreads();
  int posl = tid>>5, cg = tid&31, c0 = cg*8;
  int pos = blockIdx.x*8 + posl;
  int nb = pos>>12, h = (pos>>6)&63, w = pos&63;
  float v[8];
  #pragma unroll
  for (int k=0;k<8;k++) v[k] = lb[c0+k];
  #pragma unroll
  for (int kh=0;kh<3;kh++){
    int hin = h+kh-1;
    if (hin<0||hin>=64) continue;
    #pragma unroll
    for (int kw=0;kw<3;kw++){
      int win = w+kw-1;
      if (win<0||win>=64) continue;
      const unsigned short* xr = (const unsigned short*)xs + ((size_t)((nb*64+hin)*64+win))*256 + c0;
      ushort4 a = *(const ushort4*)xr;
      ushort4 b = *(const ushort4*)(xr+4);
      const float* wr = &lw[(kh*3+kw)*256 + c0];
      v[0] += bf2f(a.x)*wr[0]; v[1] += bf2f(a.y)*wr[1]; v[2] += bf2f(a.z)*wr[2]; v[3] += bf2f(a.w)*wr[3];
      v[4] += bf2f(b.x)*wr[4]; v[5] += bf2f(b.y)*wr[5]; v[6] += bf2f(b.z)*wr[6]; v[7] += bf2f(b.w)*wr[7];
    }
  }
  float s=0.f, s2=0.f;
  #pragma unroll
  for (int k=0;k<8;k++){ s += v[k]; s2 += v[k]*v[k]; }
  #pragma unroll
  for (int m=1;m<32;m<<=1){ s += __shfl_xor(s,m); s2 += __shfl_xor(s2,m); }
  float mu = s*(1.f/256.f);
  float var = s2*(1.f/256.f) - mu*mu;
  float rstd = rsqrtf(var + 1e-5f);
  float ge[8];
  #pragma unroll
  for (int k=0;k<8;k++){
    float xn = (v[k]-mu)*rstd*lg[c0+k] + lbt[c0+k];
    ge[k] = 0.5f*xn*(1.f + erff(xn*0.70710678118654752f));
  }
  uint4 o;
  o.x = (unsigned)f2b(ge[0]) | ((unsigned)f2b(ge[1])<<16);
  o.y = (unsigned)f2b(ge[2]) | ((unsigned)f2b(ge[3])<<16);
  o.z = (unsigned)f2b(ge[4]) | ((unsigned)f2b(ge[5])<<16);
  o.w = (unsigned)f2b(ge[6]) | ((unsigned)f2b(ge[7])<<16);
  *(uint4*)((unsigned short*)t + (size_t)pos*256 + c0) = o;
}

// ---------------- DCNv3 sampling: wave per position, 8 lanes/group x 4 ch, fused softmax ----------------
__global__ __launch_bounds__(256) void k_sample(
    const __hip_bfloat16* __restrict__ xp, const float* __restrict__ D, __hip_bfloat16* __restrict__ y)
{
  int wv = threadIdx.x >> 6;
  int lane = threadIdx.x & 63;
  int pos = blockIdx.x*4 + wv;
  int g = lane >> 3, li = lane & 7;
  int nb = pos >> 12, h = (pos >> 6) & 63, w = pos & 63;
  const float* Dp = D + (size_t)pos*216;
  const float* offp = Dp + g*18;
  const float* mskp = Dp + 144 + g*9;
  float mr[9];
  #pragma unroll
  for (int p=0;p<9;p++) mr[p] = mskp[p];
  float mx = mr[0];
  #pragma unroll
  for (int p=1;p<9;p++) mx = fmaxf(mx, mr[p]);
  float ssum = 0.f;
  #pragma unroll
  for (int p=0;p<9;p++){ mr[p] = __expf(mr[p]-mx); ssum += mr[p]; }
  float rinv = 1.f/ssum;
  const unsigned short* img = (const unsigned short*)xp + (size_t)nb*4356*256 + g*32 + li*4;
  float acc0=0.f,acc1=0.f,acc2=0.f,acc3=0.f;
  #pragma unroll
  for (int p=0;p<9;p++){
    int di = p/3 - 1, dj = p%3 - 1;
    float2 off = *(const float2*)(offp + p*2);
    float px = (float)(w + 1 + di) + off.x;
    float py = (float)(h + 1 + dj) + off.y;
    float x0f = floorf(px), y0f = floorf(py);
    float wx1 = px - x0f, wy1 = py - y0f;
    float wx0 = 1.f - wx1, wy0 = 1.f - wy1;
    int x0 = (int)x0f, y0 = (int)y0f;
    float sv0=0.f,sv1=0.f,sv2=0.f,sv3=0.f;
    #pragma unroll
    for (int cy=0;cy<2;cy++){
      int yi = y0+cy;
      if (yi<0||yi>=66) continue;
      float wy = cy ? wy1 : wy0;
      #pragma unroll
      for (int cx=0;cx<2;cx++){
        int xi = x0+cx;
        if (xi<0||xi>=66) continue;
        float wq = (cx ? wx1 : wx0)*wy;
        ushort4 v4 = *(const ushort4*)(img + (size_t)(yi*66+xi)*256);
        sv0 += bf2f(v4.x)*wq; sv1 += bf2f(v4.y)*wq; sv2 += bf2f(v4.z)*wq; sv3 += bf2f(v4.w)*wq;
      }
    }
    float mp = mr[p]*rinv;
    acc0 += sv0*mp; acc1 += sv1*mp; acc2 += sv2*mp; acc3 += sv3*mp;
  }
  ushort4 o;
  o.x = f2b(acc0); o.y = f2b(acc1); o.z = f2b(acc2); o.w = f2b(acc3);
  *(ushort4*)((unsigned short*)y + (size_t)pos*256 + g*32 + li*4) = o;
}

// ---------------- GroupNorm(32) stats: 512 blocks, atomic partials ----------------
__global__ __launch_bounds__(256) void k_gnstats(const float* __restrict__ X, float* __restrict__ stats, int npos){
  int b = blockIdx.x;       // nb(4) x grp(32) x part(4)
  int nb = b>>7, rem = b&127, grp = rem>>2, part = rem&3;
  int chunk = npos>>2;
  int cc = threadIdx.x&7, pl = threadIdx.x>>3;
  const float* base = X + ((size_t)nb*npos)*256 + grp*8 + cc;
  float s=0.f, s2=0.f;
  int pend = (part+1)*chunk;
  for (int p = part*chunk + pl; p < pend; p += 32){
    float v = base[(size_t)p*256];
    s += v; s2 += v*v;
  }
  #pragma unroll
  for (int m=1;m<64;m<<=1){ s += __shfl_xor(s,m); s2 += __shfl_xor(s2,m); }
  __shared__ float red[8];
  int wave = threadIdx.x>>6;
  if ((threadIdx.x&63)==0){ red[wave]=s; red[4+wave]=s2; }
  __syncthreads();
  if (threadIdx.x==0){
    atomicAdd(&stats[(nb*32+grp)*2+0], red[0]+red[1]+red[2]+red[3]);
    atomicAdd(&stats[(nb*32+grp)*2+1], red[4]+red[5]+red[6]+red[7]);
  }
}

// ---------------- GroupNorm apply (mu/rs from raw sums) ----------------
__global__ __launch_bounds__(256) void k_gnapply(
    const float* __restrict__ X, const float* __restrict__ stats,
    const float* __restrict__ gamma, const float* __restrict__ beta,
    float* __restrict__ OF, __hip_bfloat16* __restrict__ OH,
    int nposshift, int do_silu, int outmode)
{
  int idx = blockIdx.x*256 + threadIdx.x;
  int c = idx & 255;
  int row = idx >> 8;
  int nb = row >> nposshift;
  int p = row & ((1<<nposshift)-1);
  int grp = c >> 3;
  float S  = stats[(nb*32+grp)*2+0];
  float S2 = stats[(nb*32+grp)*2+1];
  float inv = 1.f / (float)(8 << nposshift);
  float mu = S*inv;
  float rs = rsqrtf(S2*inv - mu*mu + 1e-5f);
  float v = (X[idx] - mu) * rs * gamma[c] + beta[c];
  if (do_silu) v = v / (1.f + expf(-v));
  if (outmode == 1){
    int h = (row>>6)&63, w = row&63;
    OH[((size_t)((nb*66)+(h+1))*66 + (w+1))*256 + c] = __float2bfloat16(v);
  } else {
    OF[((size_t)(nb*256 + c) << nposshift) + p] = v;
  }
}

extern "C" void kernel_launch(void* const* d_in, const int* in_sizes, int n_in,
                              void* d_out, int out_size, void* d_ws, size_t ws_size,
                              hipStream_t stream) {
  const float* x      = (const float*)d_in[0];
  const float* w_in   = (const float*)d_in[1];
  const float* b_in   = (const float*)d_in[2];
  const float* dw_w   = (const float*)d_in[3];
  const float* dw_b   = (const float*)d_in[4];
  const float* ln_g   = (const float*)d_in[5];
  const float* ln_b   = (const float*)d_in[6];
  const float* w_off  = (const float*)d_in[7];
  const float* b_off  = (const float*)d_in[8];
  const float* w_mask = (const float*)d_in[9];
  const float* b_mask = (const float*)d_in[10];
  const float* w_out  = (const float*)d_in[11];
  const float* b_out  = (const float*)d_in[12];
  const float* gn1_g  = (const float*)d_in[13];
  const float* gn1_b  = (const float*)d_in[14];
  const float* conv1_w= (const float*)d_in[15];
  const float* conv1_b= (const float*)d_in[16];
  const float* gn2_g  = (const float*)d_in[17];
  const float* gn2_b  = (const float*)d_in[18];
  const float* down_w = (const float*)d_in[19];
  const float* down_b = (const float*)d_in[20];
  const float* gn3_g  = (const float*)d_in[21];
  const float* gn3_b  = (const float*)d_in[22];
  float* out = (float*)d_out;

  char* wsb = (char*)d_ws;
  float* R0 = (float*)wsb;                                // 16 MB fp32 (y2 / downout)
  float* R1 = (float*)(wsb + 16777216);                   // 16 MB fp32 (offmask / conv1out)
  __hip_bfloat16* R2 = (__hip_bfloat16*)(wsb + 33554432); // 8 MB bf16 (xs -> agg)
  __hip_bfloat16* R3 = (__hip_bfloat16*)(wsb + 41943040); // 8.92 MB bf16 (xp -> gn2pad)
  __hip_bfloat16* R4 = (__hip_bfloat16*)(wsb + 50864128); // 8.92 MB bf16 (t -> gn1pad)
  char* R5 = wsb + 59785216;
  __hip_bfloat16* w_inT  = (__hip_bfloat16*)R5;
  __hip_bfloat16* w_outT = (__hip_bfloat16*)(R5 + 131072);
  __hip_bfloat16* w_omT  = (__hip_bfloat16*)(R5 + 262144);
  __hip_bfloat16* c1T    = (__hip_bfloat16*)(R5 + 393216);
  __hip_bfloat16* dnT    = (__hip_bfloat16*)(R5 + 1572864);
  float* bias_om         = (float*)(R5 + 2752512);
  float* stats           = (float*)(R5 + 2753536);

  // weight prep
  k_wtrans<<<8, 256, 0, stream>>>(w_in, w_inT, 256);
  k_wtrans<<<8, 256, 0, stream>>>(w_out, w_outT, 256);
  k_wtrans<<<72, 256, 0, stream>>>(conv1_w, c1T, 2304);
  k_wtrans<<<72, 256, 0, stream>>>(down_w, dnT, 2304);
  k_womT<<<256, 256, 0, stream>>>(w_off, w_mask, b_off, b_mask, w_omT, bias_om);

  // 1. NCHW -> NHWC bf16
  k_tr<<<dim3(128,8,4), dim3(32,8), 0, stream>>>(x, R2);
  // 2. input_proj -> padded bf16 xp
  k_border<<<130, 256, 0, stream>>>(R3);
  k_mm<0,1,1,256><<<dim3(128,2), 256, 0, stream>>>(R2, w_inT, b_in, nullptr, R3);
  // 3. depthwise conv + LN + GELU -> t
  k_dwln<<<2048, 256, 0, stream>>>(R2, dw_w, dw_b, ln_g, ln_b, R4);
  // 4. fused offset+mask GEMM (softmax fused into sampler)
  k_mm<0,2,1,256><<<dim3(128,2), 256, 0, stream>>>(R4, w_omT, bias_om, R1, nullptr);
  // 5. sample -> agg (reuse R2)
  k_sample<<<4096, 256, 0, stream>>>(R3, R1, R2);
  // 6. output_proj -> y2 fp32
  k_mm<0,0,1,256><<<dim3(128,2), 256, 0, stream>>>(R2, w_outT, b_out, R0, nullptr);
  // 7. GN1 + SiLU -> padded bf16 (R4)
  hipMemsetAsync(stats, 0, 1024, stream);
  k_gnstats<<<512, 256, 0, stream>>>(R0, stats, 4096);
  k_border<<<130, 256, 0, stream>>>(R4);
  k_gnapply<<<16384, 256, 0, stream>>>(R0, stats, gn1_g, gn1_b, nullptr, R4, 12, 1, 1);
  // 8. conv1 -> R1 fp32
  k_mm<1,0,1,2304><<<dim3(128,2), 256, 0, stream>>>(R4, c1T, conv1_b, R1, nullptr);
  // 9. GN2 + SiLU -> padded bf16 (R3)
  hipMemsetAsync(stats, 0, 1024, stream);
  k_gnstats<<<512, 256, 0, stream>>>(R1, stats, 4096);
  k_border<<<130, 256, 0, stream>>>(R3);
  k_gnapply<<<16384, 256, 0, stream>>>(R1, stats, gn2_g, gn2_b, nullptr, R3, 12, 1, 1);
  // 10. down conv stride 2 -> R0
  k_mm<1,0,2,2304><<<dim3(32,2), 256, 0, stream>>>(R3, dnT, down_b, R0, nullptr);
  // 11. GN3 -> out NCHW fp32
  hipMemsetAsync(stats, 0, 1024, stream);
  k_gnstats<<<512, 256, 0, stream>>>(R0, stats, 1024);
  k_gnapply<<<4096, 256, 0, stream>>>(R0, stats, gn3_g, gn3_b, out, nullptr, 10, 0, 2);
}

// Round 4
// 262.735 us; speedup vs baseline: 3.5189x; 1.2068x over previous
//
#include <hip/hip_runtime.h>
#include <hip/hip_bf16.h>
#include <math.h>

// N=4, H=W=64, C=256, G=8, GC=32, K=3, P=9, pad=1. Padded spatial: 66x66.

typedef __attribute__((ext_vector_type(8))) short bf16x8;
typedef __attribute__((ext_vector_type(4))) float f32x4;

__device__ __forceinline__ float bf2f(unsigned short u){
  union { unsigned int i; float f; } v; v.i = ((unsigned int)u)<<16; return v.f;
}
__device__ __forceinline__ float blo(unsigned u){
  union { unsigned int i; float f; } v; v.i = u<<16; return v.f;
}
__device__ __forceinline__ float bhi(unsigned u){
  union { unsigned int i; float f; } v; v.i = u & 0xffff0000u; return v.f;
}
__device__ __forceinline__ unsigned short f2b(float f){
  __hip_bfloat16 h = __float2bfloat16(f);
  return *reinterpret_cast<unsigned short*>(&h);
}
__device__ __forceinline__ unsigned pk2(float lo, float hi){
  return (unsigned)f2b(lo) | ((unsigned)f2b(hi)<<16);
}

__device__ __forceinline__ void gload16(const void* g, void* l){
  auto gp = reinterpret_cast<const __attribute__((address_space(1))) uint32_t*>(
      reinterpret_cast<uintptr_t>(g));
  auto lp = reinterpret_cast<__attribute__((address_space(3))) uint32_t*>(
      reinterpret_cast<uintptr_t>(l));
  __builtin_amdgcn_global_load_lds(gp, lp, 16, 0, 0);
}

// ---------------- fused prep: weight transposes + offmask weight + stats zero + R3 border ----------------
__global__ __launch_bounds__(256) void k_prep(
    const float* __restrict__ w_in, const float* __restrict__ w_out,
    const float* __restrict__ conv1_w, const float* __restrict__ down_w,
    const float* __restrict__ w_off, const float* __restrict__ w_mask,
    const float* __restrict__ b_off, const float* __restrict__ b_mask,
    __hip_bfloat16* __restrict__ w_inT, __hip_bfloat16* __restrict__ w_outT,
    __hip_bfloat16* __restrict__ c1T, __hip_bfloat16* __restrict__ dnT,
    __hip_bfloat16* __restrict__ w_omT, float* __restrict__ bias_om,
    float* __restrict__ stats, __hip_bfloat16* __restrict__ R3)
{
  int b = blockIdx.x;
  if (b < 160){
    __shared__ float tl[32][257];
    const float* W; __hip_bfloat16* WT; int Kd, kb;
    if (b < 8)      { W = w_in;    WT = w_inT;  Kd = 256;  kb = b; }
    else if (b <16) { W = w_out;   WT = w_outT; Kd = 256;  kb = b-8; }
    else if (b <88) { W = conv1_w; WT = c1T;    Kd = 2304; kb = b-16; }
    else            { W = down_w;  WT = dnT;    Kd = 2304; kb = b-88; }
    int k0 = kb*32;
    #pragma unroll
    for (int dk=0; dk<32; dk++) tl[dk][threadIdx.x] = W[(size_t)(k0+dk)*256 + threadIdx.x];
    __syncthreads();
    #pragma unroll
    for (int r=0; r<32; r++){
      int co = r*8 + (threadIdx.x>>5);
      int dk = threadIdx.x&31;
      WT[(size_t)co*Kd + k0 + dk] = __float2bfloat16(tl[dk][co]);
    }
  } else if (b < 416){
    int n = b - 160, k = threadIdx.x;
    float v = (n<144) ? w_off[(size_t)k*144 + n] : (n<216 ? w_mask[(size_t)k*72 + (n-144)] : 0.f);
    w_omT[(size_t)n*256 + k] = __float2bfloat16(v);
    if (k==0) bias_om[n] = (n<144) ? b_off[n] : (n<216 ? b_mask[n-144] : 0.f);
  } else if (b < 546){
    int gid = (b-416)*8 + (threadIdx.x>>5);
    if (gid >= 1040) return;
    int n = gid/260; int ci = gid - n*260;
    int r, c;
    if (ci < 66){ r = 0; c = ci; }
    else if (ci < 132){ r = 65; c = ci-66; }
    else { int q = ci-132; r = 1 + (q>>1); c = (q&1) ? 65 : 0; }
    uint4* p = (uint4*)(R3 + ((size_t)((n*66+r)*66+c))*256) + (threadIdx.x&31);
    *p = make_uint4(0,0,0,0);
  } else {
    stats[threadIdx.x] = 0.f;
    stats[256+threadIdx.x] = 0.f;
    stats[512+threadIdx.x] = 0.f;
  }
}

// ---------------- NCHW fp32 -> NHWC bf16 ----------------
__global__ __launch_bounds__(256) void k_tr(const float* __restrict__ x, __hip_bfloat16* __restrict__ xs){
  __shared__ float tile[32][33];
  int n = blockIdx.z;
  int hw0 = blockIdx.x*32, c0 = blockIdx.y*32;
  int tx = threadIdx.x, ty = threadIdx.y; // (32,8)
  #pragma unroll
  for (int ii=0; ii<4; ii++){
    int ci = ty + ii*8;
    tile[ci][tx] = x[(size_t)(n*256 + c0+ci)*4096 + hw0 + tx];
  }
  __syncthreads();
  #pragma unroll
  for (int ii=0; ii<4; ii++){
    int hwi = ty + ii*8;
    xs[((size_t)n*4096 + hw0+hwi)*256 + c0 + tx] = __float2bfloat16(tile[tx][hwi]);
  }
}

// ---------------- MFMA GEMM / implicit conv, 64-row tiles, optional fused GN stats ----------------
// AMODE 0: A=[M][KTOT] bf16. AMODE 1: A=(4,66,66,256) padded bf16, implicit 3x3, stride STRIDE.
// OMODE 0: fp32 [M][256]+bias. OMODE 1: bf16 padded +bias. OMODE 2: fp32 ldc=216 col<216.
// NSHIFT>0: atomically accumulate per-(batch,group) sum/sumsq into stats (npos = 1<<NSHIFT).
template<int AMODE, int OMODE, int STRIDE, int KTOT, int NSHIFT>
__global__ __launch_bounds__(256) void k_mm(
    const __hip_bfloat16* __restrict__ A, const __hip_bfloat16* __restrict__ Bt,
    const float* __restrict__ bias, float* __restrict__ OF, __hip_bfloat16* __restrict__ OH,
    float* __restrict__ stats)
{
  constexpr int AROWS = 64;
  constexpr int MI = AROWS/32;            // 2
  constexpr int WROWS = AROWS/2;          // 32
  constexpr int JA = AROWS*128/4096;      // 2
  constexpr int BUFSZ = AROWS*128 + 16384;
  __shared__ uint4 lds4[2*BUFSZ/16];
  char* ldsc = (char*)lds4;
  const int tid = threadIdx.x;
  const int lane = tid & 63;
  const int wv = tid >> 6;
  const int wr = wv >> 1, wc = wv & 1;
  const int m0 = blockIdx.x * AROWS, n0 = blockIdx.y * 128;

  const int swz_s = ((tid >> 3) & 7) << 4;
  const int cby = ((tid & 7) << 4) ^ swz_s;
  const int kl = cby >> 1;
  int aoff[JA], boff[4];
  #pragma unroll
  for (int j=0;j<JA;j++){
    int row = j*32 + (tid>>3);
    if (AMODE==0){
      aoff[j] = (m0 + row) * KTOT + kl;
    } else {
      int m = m0 + row;
      int n, ho, wo;
      if (STRIDE==1){ n = m>>12; ho = (m>>6)&63; wo = m&63; }
      else          { n = m>>10; ho = (m>>5)&31; wo = m&31; }
      aoff[j] = ((n*66 + ho*STRIDE)*66 + wo*STRIDE)*256 + kl;
    }
  }
  #pragma unroll
  for (int j=0;j<4;j++) boff[j] = (n0 + j*32 + (tid>>3)) * KTOT + kl;
  char* ldsst = ldsc + wv*1024;

  const int fr = lane & 15;
  const int kb = (lane >> 4) << 4;
  const int swz_r = (fr & 7) << 4;
  int aRow[MI], bRow[4];
  #pragma unroll
  for (int i=0;i<MI;i++) aRow[i] = (wr*WROWS + i*16 + fr) * 128;
  #pragma unroll
  for (int i=0;i<4;i++)  bRow[i] = AROWS*128 + (wc*64 + i*16 + fr) * 128;
  int cb[2];
  cb[0] = kb ^ swz_r;
  cb[1] = (64 | kb) ^ swz_r;

  f32x4 acc[MI][4];
  #pragma unroll
  for (int mi=0;mi<MI;mi++)
    #pragma unroll
    for (int ni=0;ni<4;ni++)
      acc[mi][ni] = (f32x4){0.f,0.f,0.f,0.f};

  auto STAGE = [&](int buf, int t){
    const int k0 = t*64;
    int astep;
    if (AMODE==1){
      int tap = k0 >> 8;
      int kh = (tap>=6) ? 2 : (tap>=3 ? 1 : 0);
      int kw = tap - kh*3;
      astep = (kh*66 + kw)*256 + (k0 & 255);
    } else astep = k0;
    char* db = ldsst + buf*BUFSZ;
    #pragma unroll
    for (int j=0;j<JA;j++) gload16(A + aoff[j] + astep, db + j*4096);
    #pragma unroll
    for (int j=0;j<4;j++)  gload16(Bt + boff[j] + k0, db + AROWS*128 + j*4096);
  };

  constexpr int NT = KTOT / 64;
  STAGE(0, 0);
  __syncthreads();
  for (int t=0; t<NT; ++t){
    if (t+1 < NT) STAGE((t+1)&1, t+1);
    char* cbase = ldsc + (t&1)*BUFSZ;
    #pragma unroll
    for (int kk=0; kk<2; kk++){
      bf16x8 av[MI], bv[4];
      #pragma unroll
      for (int i=0;i<MI;i++) av[i] = *(const bf16x8*)(cbase + aRow[i] + cb[kk]);
      #pragma unroll
      for (int i=0;i<4;i++)  bv[i] = *(const bf16x8*)(cbase + bRow[i] + cb[kk]);
      #pragma unroll
      for (int mi=0;mi<MI;mi++)
        #pragma unroll
        for (int ni=0;ni<4;ni++)
          acc[mi][ni] = __builtin_amdgcn_mfma_f32_16x16x32_bf16(av[mi], bv[ni], acc[mi][ni], 0,0,0);
    }
    __syncthreads();
  }

  float bn[4];
  #pragma unroll
  for (int ni=0;ni<4;ni++) bn[ni] = bias[n0 + wc*64 + ni*16 + fr];
  float sni[4] = {0.f,0.f,0.f,0.f};
  float qni[4] = {0.f,0.f,0.f,0.f};
  #pragma unroll
  for (int mi=0;mi<MI;mi++){
    #pragma unroll
    for (int r=0;r<4;r++){
      int gr = m0 + wr*WROWS + mi*16 + (lane>>4)*4 + r;
      #pragma unroll
      for (int ni=0;ni<4;ni++){
        int gc = n0 + wc*64 + ni*16 + fr;
        float v = acc[mi][ni][r] + bn[ni];
        if (NSHIFT){ sni[ni] += v; qni[ni] += v*v; }
        if (OMODE==0){
          OF[(size_t)gr*256 + gc] = v;
        } else if (OMODE==1){
          int n = gr>>12, h = (gr>>6)&63, w = gr&63;
          OH[((size_t)((n*66)+(h+1))*66 + (w+1))*256 + gc] = __float2bfloat16(v);
        } else {
          if (gc < 216) OF[(size_t)gr*216 + gc] = v;
        }
      }
    }
  }
  if (NSHIFT){
    #pragma unroll
    for (int ni=0;ni<4;ni++){
      #pragma unroll
      for (int msk=16; msk<64; msk<<=1){
        sni[ni] += __shfl_xor(sni[ni], msk);
        qni[ni] += __shfl_xor(qni[ni], msk);
      }
      #pragma unroll
      for (int msk=1; msk<8; msk<<=1){
        sni[ni] += __shfl_xor(sni[ni], msk);
        qni[ni] += __shfl_xor(qni[ni], msk);
      }
    }
    float* ls = (float*)ldsc;
    if (tid < 32) ls[tid] = 0.f;
    __syncthreads();
    if ((lane & 7) == 0 && (lane & 48) == 0){
      int oct = (lane>>3) & 1;
      #pragma unroll
      for (int ni=0;ni<4;ni++){
        int idx = wc*8 + ni*2 + oct;
        atomicAdd(&ls[idx], sni[ni]);
        atomicAdd(&ls[16+idx], qni[ni]);
      }
    }
    __syncthreads();
    if (tid < 16){
      int gg = (m0>>NSHIFT)*32 + (n0>>3) + tid;
      atomicAdd(&stats[gg*2+0], ls[tid]);
      atomicAdd(&stats[gg*2+1], ls[16+tid]);
    }
  }
}

// ---------------- depthwise conv 3x3 + LayerNorm + GELU, 8ch/thread, 16B loads ----------------
__global__ __launch_bounds__(256) void k_dwln(
    const __hip_bfloat16* __restrict__ xs, const float* __restrict__ dw_w, const float* __restrict__ dw_b,
    const float* __restrict__ ln_g, const float* __restrict__ ln_b, __hip_bfloat16* __restrict__ t)
{
  __shared__ float lw[9*256];
  __shared__ float lb[256], lg[256], lbt[256];
  int tid = threadIdx.x;
  #pragma unroll
  for (int p=0;p<9;p++) lw[p*256+tid] = dw_w[p*256+tid];
  lb[tid] = dw_b[tid]; lg[tid] = ln_g[tid]; lbt[tid] = ln_b[tid];
  __syncthreads();
  int posl = tid>>5, cg = tid&31, c0 = cg*8;
  int pos = blockIdx.x*8 + posl;
  int nb = pos>>12, h = (pos>>6)&63, w = pos&63;
  float v[8];
  #pragma unroll
  for (int k=0;k<8;k++) v[k] = lb[c0+k];
  #pragma unroll
  for (int kh=0;kh<3;kh++){
    int hin = h+kh-1;
    if (hin<0||hin>=64) continue;
    #pragma unroll
    for (int kw=0;kw<3;kw++){
      int win = w+kw-1;
      if (win<0||win>=64) continue;
      const unsigned short* xr = (const unsigned short*)xs + ((size_t)((nb*64+hin)*64+win))*256 + c0;
      uint4 u = *(const uint4*)xr;
      const float* wr = &lw[(kh*3+kw)*256 + c0];
      v[0] += blo(u.x)*wr[0]; v[1] += bhi(u.x)*wr[1];
      v[2] += blo(u.y)*wr[2]; v[3] += bhi(u.y)*wr[3];
      v[4] += blo(u.z)*wr[4]; v[5] += bhi(u.z)*wr[5];
      v[6] += blo(u.w)*wr[6]; v[7] += bhi(u.w)*wr[7];
    }
  }
  float s=0.f, s2=0.f;
  #pragma unroll
  for (int k=0;k<8;k++){ s += v[k]; s2 += v[k]*v[k]; }
  #pragma unroll
  for (int m=1;m<32;m<<=1){ s += __shfl_xor(s,m); s2 += __shfl_xor(s2,m); }
  float mu = s*(1.f/256.f);
  float var = s2*(1.f/256.f) - mu*mu;
  float rstd = rsqrtf(var + 1e-5f);
  float ge[8];
  #pragma unroll
  for (int k=0;k<8;k++){
    float xn = (v[k]-mu)*rstd*lg[c0+k] + lbt[c0+k];
    ge[k] = 0.5f*xn*(1.f + erff(xn*0.70710678118654752f));
  }
  uint4 o;
  o.x = pk2(ge[0],ge[1]); o.y = pk2(ge[2],ge[3]);
  o.z = pk2(ge[4],ge[5]); o.w = pk2(ge[6],ge[7]);
  *(uint4*)((unsigned short*)t + (size_t)pos*256 + c0) = o;
}

// ---------------- DCNv3 sampling: 8ch/lane, 4 lanes/group, fused softmax ----------------
__global__ __launch_bounds__(256) void k_sample(
    const __hip_bfloat16* __restrict__ xp, const float* __restrict__ D, __hip_bfloat16* __restrict__ y)
{
  int tid = threadIdx.x;
  int pp = tid>>5;                 // 8 positions per block
  int g = (tid>>2)&7, li = tid&3;
  int pos = blockIdx.x*8 + pp;
  int nb = pos >> 12, h = (pos >> 6) & 63, w = pos & 63;
  const float* Dp = D + (size_t)pos*216;
  const float* offp = Dp + g*18;
  const float* mskp = Dp + 144 + g*9;
  float mr[9];
  #pragma unroll
  for (int p=0;p<9;p++) mr[p] = mskp[p];
  float mx = mr[0];
  #pragma unroll
  for (int p=1;p<9;p++) mx = fmaxf(mx, mr[p]);
  float ssum = 0.f;
  #pragma unroll
  for (int p=0;p<9;p++){ mr[p] = __expf(mr[p]-mx); ssum += mr[p]; }
  float rinv = 1.f/ssum;
  const unsigned short* img = (const unsigned short*)xp + (size_t)nb*4356*256 + g*32 + li*8;
  float a0=0,a1=0,a2=0,a3=0,a4=0,a5=0,a6=0,a7=0;
  #pragma unroll
  for (int p=0;p<9;p++){
    int di = p/3 - 1, dj = p%3 - 1;
    float2 off = *(const float2*)(offp + p*2);
    float px = (float)(w + 1 + di) + off.x;
    float py = (float)(h + 1 + dj) + off.y;
    float x0f = floorf(px), y0f = floorf(py);
    float wx1 = px - x0f, wy1 = py - y0f;
    float wx0 = 1.f - wx1, wy0 = 1.f - wy1;
    int x0 = (int)x0f, y0 = (int)y0f;
    float s0=0,s1=0,s2=0,s3=0,s4=0,s5=0,s6=0,s7=0;
    #pragma unroll
    for (int cy=0;cy<2;cy++){
      int yi = y0+cy;
      if (yi<0||yi>=66) continue;
      float wy = cy ? wy1 : wy0;
      #pragma unroll
      for (int cx=0;cx<2;cx++){
        int xi = x0+cx;
        if (xi<0||xi>=66) continue;
        float wq = (cx ? wx1 : wx0)*wy;
        uint4 u = *(const uint4*)(img + (size_t)(yi*66+xi)*256);
        s0 += blo(u.x)*wq; s1 += bhi(u.x)*wq;
        s2 += blo(u.y)*wq; s3 += bhi(u.y)*wq;
        s4 += blo(u.z)*wq; s5 += bhi(u.z)*wq;
        s6 += blo(u.w)*wq; s7 += bhi(u.w)*wq;
      }
    }
    float mp = mr[p]*rinv;
    a0 += s0*mp; a1 += s1*mp; a2 += s2*mp; a3 += s3*mp;
    a4 += s4*mp; a5 += s5*mp; a6 += s6*mp; a7 += s7*mp;
  }
  uint4 o;
  o.x = pk2(a0,a1); o.y = pk2(a2,a3); o.z = pk2(a4,a5); o.w = pk2(a6,a7);
  *(uint4*)((unsigned short*)y + (size_t)pos*256 + g*32 + li*8) = o;
}

// ---------------- GroupNorm apply (+SiLU) (+pad/border) (+NCHW out) ----------------
__global__ __launch_bounds__(256) void k_gnapply(
    const float* __restrict__ X, const float* __restrict__ stats,
    const float* __restrict__ gamma, const float* __restrict__ beta,
    float* __restrict__ OF, __hip_bfloat16* __restrict__ OH,
    int nposshift, int do_silu, int outmode, int nmain)
{
  if ((int)blockIdx.x >= nmain){
    int gid = (blockIdx.x - nmain)*8 + (threadIdx.x>>5);
    if (gid >= 1040) return;
    int n = gid/260; int ci = gid - n*260;
    int r, c;
    if (ci < 66){ r = 0; c = ci; }
    else if (ci < 132){ r = 65; c = ci-66; }
    else { int q = ci-132; r = 1 + (q>>1); c = (q&1) ? 65 : 0; }
    uint4* p = (uint4*)(OH + ((size_t)((n*66+r)*66+c))*256) + (threadIdx.x&31);
    *p = make_uint4(0,0,0,0);
    return;
  }
  int idx = blockIdx.x*256 + threadIdx.x;
  int c = idx & 255;
  int row = idx >> 8;
  int nb = row >> nposshift;
  int p = row & ((1<<nposshift)-1);
  int grp = c >> 3;
  float S  = stats[(nb*32+grp)*2+0];
  float S2 = stats[(nb*32+grp)*2+1];
  float inv = 1.f / (float)(8 << nposshift);
  float mu = S*inv;
  float rs = rsqrtf(S2*inv - mu*mu + 1e-5f);
  float v = (X[idx] - mu) * rs * gamma[c] + beta[c];
  if (do_silu) v = v / (1.f + expf(-v));
  if (outmode == 1){
    int h = (row>>6)&63, w = row&63;
    OH[((size_t)((nb*66)+(h+1))*66 + (w+1))*256 + c] = __float2bfloat16(v);
  } else {
    OF[((size_t)(nb*256 + c) << nposshift) + p] = v;
  }
}

extern "C" void kernel_launch(void* const* d_in, const int* in_sizes, int n_in,
                              void* d_out, int out_size, void* d_ws, size_t ws_size,
                              hipStream_t stream) {
  const float* x      = (const float*)d_in[0];
  const float* w_in   = (const float*)d_in[1];
  const float* b_in   = (const float*)d_in[2];
  const float* dw_w   = (const float*)d_in[3];
  const float* dw_b   = (const float*)d_in[4];
  const float* ln_g   = (const float*)d_in[5];
  const float* ln_b   = (const float*)d_in[6];
  const float* w_off  = (const float*)d_in[7];
  const float* b_off  = (const float*)d_in[8];
  const float* w_mask = (const float*)d_in[9];
  const float* b_mask = (const float*)d_in[10];
  const float* w_out  = (const float*)d_in[11];
  const float* b_out  = (const float*)d_in[12];
  const float* gn1_g  = (const float*)d_in[13];
  const float* gn1_b  = (const float*)d_in[14];
  const float* conv1_w= (const float*)d_in[15];
  const float* conv1_b= (const float*)d_in[16];
  const float* gn2_g  = (const float*)d_in[17];
  const float* gn2_b  = (const float*)d_in[18];
  const float* down_w = (const float*)d_in[19];
  const float* down_b = (const float*)d_in[20];
  const float* gn3_g  = (const float*)d_in[21];
  const float* gn3_b  = (const float*)d_in[22];
  float* out = (float*)d_out;

  char* wsb = (char*)d_ws;
  float* R0 = (float*)wsb;                                // 16 MB fp32 (y2 / downout)
  float* R1 = (float*)(wsb + 16777216);                   // 16 MB fp32 (offmask / conv1out)
  __hip_bfloat16* R2 = (__hip_bfloat16*)(wsb + 33554432); // 8 MB bf16 (xs -> agg)
  __hip_bfloat16* R3 = (__hip_bfloat16*)(wsb + 41943040); // 8.92 MB bf16 (xp -> gn2pad)
  __hip_bfloat16* R4 = (__hip_bfloat16*)(wsb + 50864128); // 8.92 MB bf16 (t -> gn1pad)
  char* R5 = wsb + 59785216;
  __hip_bfloat16* w_inT  = (__hip_bfloat16*)R5;
  __hip_bfloat16* w_outT = (__hip_bfloat16*)(R5 + 131072);
  __hip_bfloat16* w_omT  = (__hip_bfloat16*)(R5 + 262144);
  __hip_bfloat16* c1T    = (__hip_bfloat16*)(R5 + 393216);
  __hip_bfloat16* dnT    = (__hip_bfloat16*)(R5 + 1572864);
  float* bias_om         = (float*)(R5 + 2752512);
  float* stats           = (float*)(R5 + 2753536);        // 768 floats: GN1|GN2|GN3

  // 0. fused prep (weights, offmask, stats zero, R3 border)
  k_prep<<<547, 256, 0, stream>>>(w_in, w_out, conv1_w, down_w, w_off, w_mask, b_off, b_mask,
                                  w_inT, w_outT, c1T, dnT, w_omT, bias_om, stats, R3);
  // 1. NCHW -> NHWC bf16
  k_tr<<<dim3(128,8,4), dim3(32,8), 0, stream>>>(x, R2);
  // 2. input_proj -> padded bf16 xp (R3)
  k_mm<0,1,1,256,0><<<dim3(256,2), 256, 0, stream>>>(R2, w_inT, b_in, nullptr, R3, nullptr);
  // 3. depthwise conv + LN + GELU -> t (R4 flat)
  k_dwln<<<2048, 256, 0, stream>>>(R2, dw_w, dw_b, ln_g, ln_b, R4);
  // 4. fused offset+mask GEMM
  k_mm<0,2,1,256,0><<<dim3(256,2), 256, 0, stream>>>(R4, w_omT, bias_om, R1, nullptr, nullptr);
  // 5. sample -> agg (R2)
  k_sample<<<2048, 256, 0, stream>>>(R3, R1, R2);
  // 6. output_proj -> R0 fp32, + GN1 stats
  k_mm<0,0,1,256,12><<<dim3(256,2), 256, 0, stream>>>(R2, w_outT, b_out, R0, nullptr, stats);
  // 7. GN1 + SiLU -> padded bf16 (R4) + border
  k_gnapply<<<16384+130, 256, 0, stream>>>(R0, stats, gn1_g, gn1_b, nullptr, R4, 12, 1, 1, 16384);
  // 8. conv1 -> R1 fp32, + GN2 stats
  k_mm<1,0,1,2304,12><<<dim3(256,2), 256, 0, stream>>>(R4, c1T, conv1_b, R1, nullptr, stats+256);
  // 9. GN2 + SiLU -> padded bf16 (R3) + border
  k_gnapply<<<16384+130, 256, 0, stream>>>(R1, stats+256, gn2_g, gn2_b, nullptr, R3, 12, 1, 1, 16384);
  // 10. down conv stride 2 -> R0, + GN3 stats
  k_mm<1,0,2,2304,10><<<dim3(64,2), 256, 0, stream>>>(R3, dnT, down_b, R0, nullptr, stats+512);
  // 11. GN3 -> out NCHW fp32
  k_gnapply<<<4096, 256, 0, stream>>>(R0, stats+512, gn3_g, gn3_b, out, nullptr, 10, 0, 2, 4096);
}

// Round 5
// 246.714 us; speedup vs baseline: 3.7474x; 1.0649x over previous
//
#include <hip/hip_runtime.h>
#include <hip/hip_bf16.h>
#include <math.h>

// N=4, H=W=64, C=256, G=8, GC=32, K=3, P=9, pad=1. Padded spatial: 66x66.

typedef __attribute__((ext_vector_type(8))) short bf16x8;
typedef __attribute__((ext_vector_type(4))) float f32x4;

__device__ __forceinline__ float blo(unsigned u){
  union { unsigned int i; float f; } v; v.i = u<<16; return v.f;
}
__device__ __forceinline__ float bhi(unsigned u){
  union { unsigned int i; float f; } v; v.i = u & 0xffff0000u; return v.f;
}
__device__ __forceinline__ unsigned short f2b(float f){
  __hip_bfloat16 h = __float2bfloat16(f);
  return *reinterpret_cast<unsigned short*>(&h);
}
__device__ __forceinline__ unsigned pk2(float lo, float hi){
  return (unsigned)f2b(lo) | ((unsigned)f2b(hi)<<16);
}

__device__ __forceinline__ void gload16(const void* g, void* l){
  auto gp = reinterpret_cast<const __attribute__((address_space(1))) uint32_t*>(
      reinterpret_cast<uintptr_t>(g));
  auto lp = reinterpret_cast<__attribute__((address_space(3))) uint32_t*>(
      reinterpret_cast<uintptr_t>(l));
  __builtin_amdgcn_global_load_lds(gp, lp, 16, 0, 0);
}

// ---------------- fused prep: weight transposes + offmask + stats zero + R3 border + NCHW->NHWC ----------------
__global__ __launch_bounds__(256) void k_prep(
    const float* __restrict__ x,
    const float* __restrict__ w_in, const float* __restrict__ w_out,
    const float* __restrict__ conv1_w, const float* __restrict__ down_w,
    const float* __restrict__ w_off, const float* __restrict__ w_mask,
    const float* __restrict__ b_off, const float* __restrict__ b_mask,
    __hip_bfloat16* __restrict__ w_inT, __hip_bfloat16* __restrict__ w_outT,
    __hip_bfloat16* __restrict__ c1T, __hip_bfloat16* __restrict__ dnT,
    __hip_bfloat16* __restrict__ w_omT, float* __restrict__ bias_om,
    float* __restrict__ stats, __hip_bfloat16* __restrict__ R3,
    __hip_bfloat16* __restrict__ xs)
{
  int b = blockIdx.x;
  if (b < 160){
    __shared__ float tl[32][257];
    const float* W; __hip_bfloat16* WT; int Kd, kb;
    if (b < 8)      { W = w_in;    WT = w_inT;  Kd = 256;  kb = b; }
    else if (b <16) { W = w_out;   WT = w_outT; Kd = 256;  kb = b-8; }
    else if (b <88) { W = conv1_w; WT = c1T;    Kd = 2304; kb = b-16; }
    else            { W = down_w;  WT = dnT;    Kd = 2304; kb = b-88; }
    int k0 = kb*32;
    #pragma unroll
    for (int dk=0; dk<32; dk++) tl[dk][threadIdx.x] = W[(size_t)(k0+dk)*256 + threadIdx.x];
    __syncthreads();
    #pragma unroll
    for (int r=0; r<32; r++){
      int co = r*8 + (threadIdx.x>>5);
      int dk = threadIdx.x&31;
      WT[(size_t)co*Kd + k0 + dk] = __float2bfloat16(tl[dk][co]);
    }
  } else if (b < 416){
    int n = b - 160, k = threadIdx.x;
    float v = (n<144) ? w_off[(size_t)k*144 + n] : (n<216 ? w_mask[(size_t)k*72 + (n-144)] : 0.f);
    w_omT[(size_t)n*256 + k] = __float2bfloat16(v);
    if (k==0) bias_om[n] = (n<144) ? b_off[n] : (n<216 ? b_mask[n-144] : 0.f);
  } else if (b < 546){
    int gid = (b-416)*8 + (threadIdx.x>>5);
    if (gid >= 1040) return;
    int n = gid/260; int ci = gid - n*260;
    int r, c;
    if (ci < 66){ r = 0; c = ci; }
    else if (ci < 132){ r = 65; c = ci-66; }
    else { int q = ci-132; r = 1 + (q>>1); c = (q&1) ? 65 : 0; }
    uint4* p = (uint4*)(R3 + ((size_t)((n*66+r)*66+c))*256) + (threadIdx.x&31);
    *p = make_uint4(0,0,0,0);
  } else if (b == 546){
    stats[threadIdx.x] = 0.f;
    stats[256+threadIdx.x] = 0.f;
    stats[512+threadIdx.x] = 0.f;
  } else {
    // NCHW fp32 -> NHWC bf16 transpose, 32x32 tile
    __shared__ float tile[32][33];
    int t = b - 547;                 // 0..4095
    int n = t >> 10;
    int c0 = ((t >> 7) & 7) * 32;
    int hw0 = (t & 127) * 32;
    int tx = threadIdx.x & 31, ty = threadIdx.x >> 5;
    #pragma unroll
    for (int ii=0; ii<4; ii++){
      int ci = ty + ii*8;
      tile[ci][tx] = x[(size_t)(n*256 + c0+ci)*4096 + hw0 + tx];
    }
    __syncthreads();
    #pragma unroll
    for (int ii=0; ii<4; ii++){
      int hwi = ty + ii*8;
      xs[((size_t)n*4096 + hw0+hwi)*256 + c0 + tx] = __float2bfloat16(tile[tx][hwi]);
    }
  }
}

// ---------------- MFMA GEMM / implicit conv, 64-row tiles, XCD swizzle, fused GN stats ----------------
// AMODE 0: A=[M][KTOT] bf16. AMODE 1: A=(4,66,66,256) padded bf16, implicit 3x3, stride STRIDE.
// OMODE 0: bf16 [M][256]+bias. OMODE 1: bf16 padded +bias. OMODE 2: fp32 ldc=216 col<216.
// NSHIFT>0: accumulate per-(batch,group) sum/sumsq into stats.
template<int AMODE, int OMODE, int STRIDE, int KTOT, int NSHIFT>
__global__ __launch_bounds__(256) void k_mm(
    const __hip_bfloat16* __restrict__ A, const __hip_bfloat16* __restrict__ Bt,
    const float* __restrict__ bias, float* __restrict__ OF, __hip_bfloat16* __restrict__ OH,
    float* __restrict__ stats)
{
  constexpr int AROWS = 64;
  constexpr int MI = AROWS/32;            // 2
  constexpr int WROWS = AROWS/2;          // 32
  constexpr int JA = AROWS*128/4096;      // 2
  constexpr int BUFSZ = AROWS*128 + 16384;
  __shared__ uint4 lds4[2*BUFSZ/16];
  char* ldsc = (char*)lds4;
  const int tid = threadIdx.x;
  const int lane = tid & 63;
  const int wv = tid >> 6;
  const int wr = wv >> 1, wc = wv & 1;

  // XCD-chunked bijective swizzle (nwg % 8 == 0 for all launches)
  int id = blockIdx.y * gridDim.x + blockIdx.x;
  int cpx = (gridDim.x * gridDim.y) >> 3;
  int sw = (id & 7) * cpx + (id >> 3);
  const int m0 = (sw >> 1) * AROWS, n0 = (sw & 1) * 128;

  const int swz_s = ((tid >> 3) & 7) << 4;
  const int cby = ((tid & 7) << 4) ^ swz_s;
  const int kl = cby >> 1;
  int aoff[JA], boff[4];
  #pragma unroll
  for (int j=0;j<JA;j++){
    int row = j*32 + (tid>>3);
    if (AMODE==0){
      aoff[j] = (m0 + row) * KTOT + kl;
    } else {
      int m = m0 + row;
      int n, ho, wo;
      if (STRIDE==1){ n = m>>12; ho = (m>>6)&63; wo = m&63; }
      else          { n = m>>10; ho = (m>>5)&31; wo = m&31; }
      aoff[j] = ((n*66 + ho*STRIDE)*66 + wo*STRIDE)*256 + kl;
    }
  }
  #pragma unroll
  for (int j=0;j<4;j++) boff[j] = (n0 + j*32 + (tid>>3)) * KTOT + kl;
  char* ldsst = ldsc + wv*1024;

  const int fr = lane & 15;
  const int kb = (lane >> 4) << 4;
  const int swz_r = (fr & 7) << 4;
  int aRow[MI], bRow[4];
  #pragma unroll
  for (int i=0;i<MI;i++) aRow[i] = (wr*WROWS + i*16 + fr) * 128;
  #pragma unroll
  for (int i=0;i<4;i++)  bRow[i] = AROWS*128 + (wc*64 + i*16 + fr) * 128;
  int cb[2];
  cb[0] = kb ^ swz_r;
  cb[1] = (64 | kb) ^ swz_r;

  f32x4 acc[MI][4];
  #pragma unroll
  for (int mi=0;mi<MI;mi++)
    #pragma unroll
    for (int ni=0;ni<4;ni++)
      acc[mi][ni] = (f32x4){0.f,0.f,0.f,0.f};

  auto STAGE = [&](int buf, int t){
    const int k0 = t*64;
    int astep;
    if (AMODE==1){
      int tap = k0 >> 8;
      int kh = (tap>=6) ? 2 : (tap>=3 ? 1 : 0);
      int kw = tap - kh*3;
      astep = (kh*66 + kw)*256 + (k0 & 255);
    } else astep = k0;
    char* db = ldsst + buf*BUFSZ;
    #pragma unroll
    for (int j=0;j<JA;j++) gload16(A + aoff[j] + astep, db + j*4096);
    #pragma unroll
    for (int j=0;j<4;j++)  gload16(Bt + boff[j] + k0, db + AROWS*128 + j*4096);
  };

  constexpr int NT = KTOT / 64;
  STAGE(0, 0);
  __syncthreads();
  for (int t=0; t<NT; ++t){
    if (t+1 < NT) STAGE((t+1)&1, t+1);
    char* cbase = ldsc + (t&1)*BUFSZ;
    #pragma unroll
    for (int kk=0; kk<2; kk++){
      bf16x8 av[MI], bv[4];
      #pragma unroll
      for (int i=0;i<MI;i++) av[i] = *(const bf16x8*)(cbase + aRow[i] + cb[kk]);
      #pragma unroll
      for (int i=0;i<4;i++)  bv[i] = *(const bf16x8*)(cbase + bRow[i] + cb[kk]);
      #pragma unroll
      for (int mi=0;mi<MI;mi++)
        #pragma unroll
        for (int ni=0;ni<4;ni++)
          acc[mi][ni] = __builtin_amdgcn_mfma_f32_16x16x32_bf16(av[mi], bv[ni], acc[mi][ni], 0,0,0);
    }
    __syncthreads();
  }

  float bn[4];
  #pragma unroll
  for (int ni=0;ni<4;ni++) bn[ni] = bias[n0 + wc*64 + ni*16 + fr];
  float sni[4] = {0.f,0.f,0.f,0.f};
  float qni[4] = {0.f,0.f,0.f,0.f};
  #pragma unroll
  for (int mi=0;mi<MI;mi++){
    #pragma unroll
    for (int r=0;r<4;r++){
      int gr = m0 + wr*WROWS + mi*16 + (lane>>4)*4 + r;
      #pragma unroll
      for (int ni=0;ni<4;ni++){
        int gc = n0 + wc*64 + ni*16 + fr;
        float v = acc[mi][ni][r] + bn[ni];
        if (NSHIFT){ sni[ni] += v; qni[ni] += v*v; }
        if (OMODE==0){
          OH[(size_t)gr*256 + gc] = __float2bfloat16(v);
        } else if (OMODE==1){
          int n = gr>>12, h = (gr>>6)&63, w = gr&63;
          OH[((size_t)((n*66)+(h+1))*66 + (w+1))*256 + gc] = __float2bfloat16(v);
        } else {
          if (gc < 216) OF[(size_t)gr*216 + gc] = v;
        }
      }
    }
  }
  if (NSHIFT){
    #pragma unroll
    for (int ni=0;ni<4;ni++){
      #pragma unroll
      for (int msk=16; msk<64; msk<<=1){
        sni[ni] += __shfl_xor(sni[ni], msk);
        qni[ni] += __shfl_xor(qni[ni], msk);
      }
      #pragma unroll
      for (int msk=1; msk<8; msk<<=1){
        sni[ni] += __shfl_xor(sni[ni], msk);
        qni[ni] += __shfl_xor(qni[ni], msk);
      }
    }
    float* ls = (float*)ldsc;
    if (tid < 32) ls[tid] = 0.f;
    __syncthreads();
    if ((lane & 7) == 0 && (lane & 48) == 0){
      int oct = (lane>>3) & 1;
      #pragma unroll
      for (int ni=0;ni<4;ni++){
        int idx = wc*8 + ni*2 + oct;
        atomicAdd(&ls[idx], sni[ni]);
        atomicAdd(&ls[16+idx], qni[ni]);
      }
    }
    __syncthreads();
    if (tid < 16){
      int gg = (m0>>NSHIFT)*32 + (n0>>3) + tid;
      atomicAdd(&stats[gg*2+0], ls[tid]);
      atomicAdd(&stats[gg*2+1], ls[16+tid]);
    }
  }
}

// ---------------- depthwise conv 3x3 + LayerNorm + GELU, 8ch/thread, 16B loads ----------------
__global__ __launch_bounds__(256) void k_dwln(
    const __hip_bfloat16* __restrict__ xs, const float* __restrict__ dw_w, const float* __restrict__ dw_b,
    const float* __restrict__ ln_g, const float* __restrict__ ln_b, __hip_bfloat16* __restrict__ t)
{
  __shared__ float lw[9*256];
  __shared__ float lb[256], lg[256], lbt[256];
  int tid = threadIdx.x;
  #pragma unroll
  for (int p=0;p<9;p++) lw[p*256+tid] = dw_w[p*256+tid];
  lb[tid] = dw_b[tid]; lg[tid] = ln_g[tid]; lbt[tid] = ln_b[tid];
  __syncthreads();
  int posl = tid>>5, cg = tid&31, c0 = cg*8;
  int pos = blockIdx.x*8 + posl;
  int nb = pos>>12, h = (pos>>6)&63, w = pos&63;
  float v[8];
  #pragma unroll
  for (int k=0;k<8;k++) v[k] = lb[c0+k];
  #pragma unroll
  for (int kh=0;kh<3;kh++){
    int hin = h+kh-1;
    if (hin<0||hin>=64) continue;
    #pragma unroll
    for (int kw=0;kw<3;kw++){
      int win = w+kw-1;
      if (win<0||win>=64) continue;
      const unsigned short* xr = (const unsigned short*)xs + ((size_t)((nb*64+hin)*64+win))*256 + c0;
      uint4 u = *(const uint4*)xr;
      const float* wr = &lw[(kh*3+kw)*256 + c0];
      v[0] += blo(u.x)*wr[0]; v[1] += bhi(u.x)*wr[1];
      v[2] += blo(u.y)*wr[2]; v[3] += bhi(u.y)*wr[3];
      v[4] += blo(u.z)*wr[4]; v[5] += bhi(u.z)*wr[5];
      v[6] += blo(u.w)*wr[6]; v[7] += bhi(u.w)*wr[7];
    }
  }
  float s=0.f, s2=0.f;
  #pragma unroll
  for (int k=0;k<8;k++){ s += v[k]; s2 += v[k]*v[k]; }
  #pragma unroll
  for (int m=1;m<32;m<<=1){ s += __shfl_xor(s,m); s2 += __shfl_xor(s2,m); }
  float mu = s*(1.f/256.f);
  float var = s2*(1.f/256.f) - mu*mu;
  float rstd = rsqrtf(var + 1e-5f);
  float ge[8];
  #pragma unroll
  for (int k=0;k<8;k++){
    float xn = (v[k]-mu)*rstd*lg[c0+k] + lbt[c0+k];
    ge[k] = 0.5f*xn*(1.f + erff(xn*0.70710678118654752f));
  }
  uint4 o;
  o.x = pk2(ge[0],ge[1]); o.y = pk2(ge[2],ge[3]);
  o.z = pk2(ge[4],ge[5]); o.w = pk2(ge[6],ge[7]);
  *(uint4*)((unsigned short*)t + (size_t)pos*256 + c0) = o;
}

// ---------------- DCNv3 sampling: 8ch/lane, 4 lanes/group, fused softmax ----------------
__global__ __launch_bounds__(256) void k_sample(
    const __hip_bfloat16* __restrict__ xp, const float* __restrict__ D, __hip_bfloat16* __restrict__ y)
{
  int tid = threadIdx.x;
  int pp = tid>>5;
  int g = (tid>>2)&7, li = tid&3;
  int pos = blockIdx.x*8 + pp;
  int nb = pos >> 12, h = (pos >> 6) & 63, w = pos & 63;
  const float* Dp = D + (size_t)pos*216;
  const float* offp = Dp + g*18;
  const float* mskp = Dp + 144 + g*9;
  float mr[9];
  #pragma unroll
  for (int p=0;p<9;p++) mr[p] = mskp[p];
  float mx = mr[0];
  #pragma unroll
  for (int p=1;p<9;p++) mx = fmaxf(mx, mr[p]);
  float ssum = 0.f;
  #pragma unroll
  for (int p=0;p<9;p++){ mr[p] = __expf(mr[p]-mx); ssum += mr[p]; }
  float rinv = 1.f/ssum;
  const unsigned short* img = (const unsigned short*)xp + (size_t)nb*4356*256 + g*32 + li*8;
  float a0=0,a1=0,a2=0,a3=0,a4=0,a5=0,a6=0,a7=0;
  #pragma unroll
  for (int p=0;p<9;p++){
    int di = p/3 - 1, dj = p%3 - 1;
    float2 off = *(const float2*)(offp + p*2);
    float px = (float)(w + 1 + di) + off.x;
    float py = (float)(h + 1 + dj) + off.y;
    float x0f = floorf(px), y0f = floorf(py);
    float wx1 = px - x0f, wy1 = py - y0f;
    float wx0 = 1.f - wx1, wy0 = 1.f - wy1;
    int x0 = (int)x0f, y0 = (int)y0f;
    float s0=0,s1=0,s2=0,s3=0,s4=0,s5=0,s6=0,s7=0;
    #pragma unroll
    for (int cy=0;cy<2;cy++){
      int yi = y0+cy;
      if (yi<0||yi>=66) continue;
      float wy = cy ? wy1 : wy0;
      #pragma unroll
      for (int cx=0;cx<2;cx++){
        int xi = x0+cx;
        if (xi<0||xi>=66) continue;
        float wq = (cx ? wx1 : wx0)*wy;
        uint4 u = *(const uint4*)(img + (size_t)(yi*66+xi)*256);
        s0 += blo(u.x)*wq; s1 += bhi(u.x)*wq;
        s2 += blo(u.y)*wq; s3 += bhi(u.y)*wq;
        s4 += blo(u.z)*wq; s5 += bhi(u.z)*wq;
        s6 += blo(u.w)*wq; s7 += bhi(u.w)*wq;
      }
    }
    float mp = mr[p]*rinv;
    a0 += s0*mp; a1 += s1*mp; a2 += s2*mp; a3 += s3*mp;
    a4 += s4*mp; a5 += s5*mp; a6 += s6*mp; a7 += s7*mp;
  }
  uint4 o;
  o.x = pk2(a0,a1); o.y = pk2(a2,a3); o.z = pk2(a4,a5); o.w = pk2(a6,a7);
  *(uint4*)((unsigned short*)y + (size_t)pos*256 + g*32 + li*8) = o;
}

// ---------------- GN apply + SiLU -> padded bf16 (+border), 8ch/thread, bf16 in ----------------
__global__ __launch_bounds__(256) void k_gnapply(
    const __hip_bfloat16* __restrict__ X, const float* __restrict__ stats,
    const float* __restrict__ gamma, const float* __restrict__ beta,
    __hip_bfloat16* __restrict__ OH, int nmain)
{
  int b = blockIdx.x;
  int tid = threadIdx.x;
  if (b >= nmain){
    int gid = (b - nmain)*8 + (tid>>5);
    if (gid >= 1040) return;
    int n = gid/260; int ci = gid - n*260;
    int r, c;
    if (ci < 66){ r = 0; c = ci; }
    else if (ci < 132){ r = 65; c = ci-66; }
    else { int q = ci-132; r = 1 + (q>>1); c = (q&1) ? 65 : 0; }
    uint4* p = (uint4*)(OH + ((size_t)((n*66+r)*66+c))*256) + (tid&31);
    *p = make_uint4(0,0,0,0);
    return;
  }
  int row = b*8 + (tid>>5);
  int grp = tid & 31;
  int c0 = grp*8;
  int nb = row >> 12;
  float S  = stats[(nb*32+grp)*2+0];
  float S2 = stats[(nb*32+grp)*2+1];
  const float inv = 1.f/32768.f;
  float mu = S*inv;
  float rs = rsqrtf(S2*inv - mu*mu + 1e-5f);
  float4 g0 = *(const float4*)(gamma + c0), g1 = *(const float4*)(gamma + c0 + 4);
  float4 bt0 = *(const float4*)(beta + c0), bt1 = *(const float4*)(beta + c0 + 4);
  uint4 u = *(const uint4*)((const unsigned short*)X + (size_t)row*256 + c0);
  float v[8] = { blo(u.x), bhi(u.x), blo(u.y), bhi(u.y), blo(u.z), bhi(u.z), blo(u.w), bhi(u.w) };
  float gm[8] = { g0.x,g0.y,g0.z,g0.w,g1.x,g1.y,g1.z,g1.w };
  float bb[8] = { bt0.x,bt0.y,bt0.z,bt0.w,bt1.x,bt1.y,bt1.z,bt1.w };
  #pragma unroll
  for (int k=0;k<8;k++){
    float t = (v[k]-mu)*rs*gm[k] + bb[k];
    v[k] = t / (1.f + expf(-t));
  }
  int h = (row>>6)&63, w = row&63;
  uint4 o;
  o.x = pk2(v[0],v[1]); o.y = pk2(v[2],v[3]); o.z = pk2(v[4],v[5]); o.w = pk2(v[6],v[7]);
  *(uint4*)((unsigned short*)OH + ((size_t)((nb*66)+(h+1))*66 + (w+1))*256 + c0) = o;
}

// ---------------- GN3 apply -> fp32 NCHW out, LDS transpose for coalesced write ----------------
__global__ __launch_bounds__(256) void k_gnout(
    const __hip_bfloat16* __restrict__ X, const float* __restrict__ stats,
    const float* __restrict__ gamma, const float* __restrict__ beta, float* __restrict__ out)
{
  __shared__ float val[8][1024];
  int nb = blockIdx.x >> 5, cg = blockIdx.x & 31;
  int c0 = cg*8;
  float S  = stats[(nb*32+cg)*2+0];
  float S2 = stats[(nb*32+cg)*2+1];
  const float inv = 1.f/8192.f;
  float mu = S*inv;
  float rs = rsqrtf(S2*inv - mu*mu + 1e-5f);
  float4 g0 = *(const float4*)(gamma + c0), g1 = *(const float4*)(gamma + c0 + 4);
  float4 bt0 = *(const float4*)(beta + c0), bt1 = *(const float4*)(beta + c0 + 4);
  float gm[8] = { g0.x,g0.y,g0.z,g0.w,g1.x,g1.y,g1.z,g1.w };
  float bb[8] = { bt0.x,bt0.y,bt0.z,bt0.w,bt1.x,bt1.y,bt1.z,bt1.w };
  #pragma unroll
  for (int k=0;k<4;k++){
    int pos = k*256 + threadIdx.x;
    uint4 u = *(const uint4*)((const unsigned short*)X + ((size_t)(nb*1024+pos))*256 + c0);
    float v[8] = { blo(u.x), bhi(u.x), blo(u.y), bhi(u.y), blo(u.z), bhi(u.z), blo(u.w), bhi(u.w) };
    #pragma unroll
    for (int q=0;q<8;q++) val[q][pos] = (v[q]-mu)*rs*gm[q] + bb[q];
  }
  __syncthreads();
  int ch = threadIdx.x>>5, pl = threadIdx.x&31;
  float* orow = out + (((size_t)(nb*256 + c0 + ch))<<10);
  #pragma unroll
  for (int j=0;j<32;j++) orow[pl + j*32] = val[ch][pl + j*32];
}

extern "C" void kernel_launch(void* const* d_in, const int* in_sizes, int n_in,
                              void* d_out, int out_size, void* d_ws, size_t ws_size,
                              hipStream_t stream) {
  const float* x      = (const float*)d_in[0];
  const float* w_in   = (const float*)d_in[1];
  const float* b_in   = (const float*)d_in[2];
  const float* dw_w   = (const float*)d_in[3];
  const float* dw_b   = (const float*)d_in[4];
  const float* ln_g   = (const float*)d_in[5];
  const float* ln_b   = (const float*)d_in[6];
  const float* w_off  = (const float*)d_in[7];
  const float* b_off  = (const float*)d_in[8];
  const float* w_mask = (const float*)d_in[9];
  const float* b_mask = (const float*)d_in[10];
  const float* w_out  = (const float*)d_in[11];
  const float* b_out  = (const float*)d_in[12];
  const float* gn1_g  = (const float*)d_in[13];
  const float* gn1_b  = (const float*)d_in[14];
  const float* conv1_w= (const float*)d_in[15];
  const float* conv1_b= (const float*)d_in[16];
  const float* gn2_g  = (const float*)d_in[17];
  const float* gn2_b  = (const float*)d_in[18];
  const float* down_w = (const float*)d_in[19];
  const float* down_b = (const float*)d_in[20];
  const float* gn3_g  = (const float*)d_in[21];
  const float* gn3_b  = (const float*)d_in[22];
  float* out = (float*)d_out;

  char* wsb = (char*)d_ws;
  __hip_bfloat16* R0h = (__hip_bfloat16*)wsb;             // 8 MB bf16 (y2 / down-out)
  float* R1f = (float*)(wsb + 16777216);                  // 14.2 MB fp32 (offmask) / bf16 conv1-out
  __hip_bfloat16* R1h = (__hip_bfloat16*)(wsb + 16777216);
  __hip_bfloat16* R2 = (__hip_bfloat16*)(wsb + 33554432); // 8 MB bf16 (xs -> agg)
  __hip_bfloat16* R3 = (__hip_bfloat16*)(wsb + 41943040); // 8.92 MB bf16 (xp -> gn2pad)
  __hip_bfloat16* R4 = (__hip_bfloat16*)(wsb + 50864128); // 8.92 MB bf16 (t -> gn1pad)
  char* R5 = wsb + 59785216;
  __hip_bfloat16* w_inT  = (__hip_bfloat16*)R5;
  __hip_bfloat16* w_outT = (__hip_bfloat16*)(R5 + 131072);
  __hip_bfloat16* w_omT  = (__hip_bfloat16*)(R5 + 262144);
  __hip_bfloat16* c1T    = (__hip_bfloat16*)(R5 + 393216);
  __hip_bfloat16* dnT    = (__hip_bfloat16*)(R5 + 1572864);
  float* bias_om         = (float*)(R5 + 2752512);
  float* stats           = (float*)(R5 + 2753536);        // 768 floats: GN1|GN2|GN3

  // 0. fused prep (weights, offmask, R3 border, stats zero, NCHW->NHWC)
  k_prep<<<4643, 256, 0, stream>>>(x, w_in, w_out, conv1_w, down_w, w_off, w_mask, b_off, b_mask,
                                   w_inT, w_outT, c1T, dnT, w_omT, bias_om, stats, R3, R2);
  // 1. input_proj -> padded bf16 xp (R3)
  k_mm<0,1,1,256,0><<<dim3(256,2), 256, 0, stream>>>(R2, w_inT, b_in, nullptr, R3, nullptr);
  // 2. depthwise conv + LN + GELU -> t (R4 flat)
  k_dwln<<<2048, 256, 0, stream>>>(R2, dw_w, dw_b, ln_g, ln_b, R4);
  // 3. fused offset+mask GEMM -> R1 fp32
  k_mm<0,2,1,256,0><<<dim3(256,2), 256, 0, stream>>>(R4, w_omT, bias_om, R1f, nullptr, nullptr);
  // 4. sample -> agg (R2)
  k_sample<<<2048, 256, 0, stream>>>(R3, R1f, R2);
  // 5. output_proj -> R0 bf16 + GN1 stats
  k_mm<0,0,1,256,12><<<dim3(256,2), 256, 0, stream>>>(R2, w_outT, b_out, nullptr, R0h, stats);
  // 6. GN1 + SiLU -> padded bf16 (R4) + border
  k_gnapply<<<2048+130, 256, 0, stream>>>(R0h, stats, gn1_g, gn1_b, R4, 2048);
  // 7. conv1 -> R1 bf16 + GN2 stats
  k_mm<1,0,1,2304,12><<<dim3(256,2), 256, 0, stream>>>(R4, c1T, conv1_b, nullptr, R1h, stats+256);
  // 8. GN2 + SiLU -> padded bf16 (R3) + border
  k_gnapply<<<2048+130, 256, 0, stream>>>(R1h, stats+256, gn2_g, gn2_b, R3, 2048);
  // 9. down conv stride 2 -> R0 bf16 + GN3 stats
  k_mm<1,0,2,2304,10><<<dim3(64,2), 256, 0, stream>>>(R3, dnT, down_b, nullptr, R0h, stats+512);
  // 10. GN3 -> out NCHW fp32 (coalesced via LDS transpose)
  k_gnout<<<128, 256, 0, stream>>>(R0h, stats+512, gn3_g, gn3_b, out);
}

// Round 6
// 235.325 us; speedup vs baseline: 3.9287x; 1.0484x over previous
//
#include <hip/hip_runtime.h>
#include <hip/hip_bf16.h>
#include <math.h>

// N=4, H=W=64, C=256, G=8, GC=32, K=3, P=9, pad=1. Padded spatial: 66x66.

typedef __attribute__((ext_vector_type(8))) short bf16x8;
typedef __attribute__((ext_vector_type(4))) float f32x4;

__device__ __forceinline__ float blo(unsigned u){
  union { unsigned int i; float f; } v; v.i = u<<16; return v.f;
}
__device__ __forceinline__ float bhi(unsigned u){
  union { unsigned int i; float f; } v; v.i = u & 0xffff0000u; return v.f;
}
__device__ __forceinline__ unsigned short f2b(float f){
  __hip_bfloat16 h = __float2bfloat16(f);
  return *reinterpret_cast<unsigned short*>(&h);
}
__device__ __forceinline__ unsigned pk2(float lo, float hi){
  return (unsigned)f2b(lo) | ((unsigned)f2b(hi)<<16);
}

__device__ __forceinline__ void gload16(const void* g, void* l){
  auto gp = reinterpret_cast<const __attribute__((address_space(1))) uint32_t*>(
      reinterpret_cast<uintptr_t>(g));
  auto lp = reinterpret_cast<__attribute__((address_space(3))) uint32_t*>(
      reinterpret_cast<uintptr_t>(l));
  __builtin_amdgcn_global_load_lds(gp, lp, 16, 0, 0);
}

// ---------------- fused prep: weight transposes + offmask + stats zero + R3 border + NCHW->NHWC ----------------
__global__ __launch_bounds__(256) void k_prep(
    const float* __restrict__ x,
    const float* __restrict__ w_in, const float* __restrict__ w_out,
    const float* __restrict__ conv1_w, const float* __restrict__ down_w,
    const float* __restrict__ w_off, const float* __restrict__ w_mask,
    const float* __restrict__ b_off, const float* __restrict__ b_mask,
    __hip_bfloat16* __restrict__ w_inT, __hip_bfloat16* __restrict__ w_outT,
    __hip_bfloat16* __restrict__ c1T, __hip_bfloat16* __restrict__ dnT,
    __hip_bfloat16* __restrict__ w_omT, float* __restrict__ bias_om,
    float* __restrict__ stats, __hip_bfloat16* __restrict__ R3,
    __hip_bfloat16* __restrict__ xs)
{
  int b = blockIdx.x;
  if (b < 160){
    __shared__ float tl[32][257];
    const float* W; __hip_bfloat16* WT; int Kd, kb;
    if (b < 8)      { W = w_in;    WT = w_inT;  Kd = 256;  kb = b; }
    else if (b <16) { W = w_out;   WT = w_outT; Kd = 256;  kb = b-8; }
    else if (b <88) { W = conv1_w; WT = c1T;    Kd = 2304; kb = b-16; }
    else            { W = down_w;  WT = dnT;    Kd = 2304; kb = b-88; }
    int k0 = kb*32;
    #pragma unroll
    for (int dk=0; dk<32; dk++) tl[dk][threadIdx.x] = W[(size_t)(k0+dk)*256 + threadIdx.x];
    __syncthreads();
    #pragma unroll
    for (int r=0; r<32; r++){
      int co = r*8 + (threadIdx.x>>5);
      int dk = threadIdx.x&31;
      WT[(size_t)co*Kd + k0 + dk] = __float2bfloat16(tl[dk][co]);
    }
  } else if (b < 416){
    int n = b - 160, k = threadIdx.x;
    float v = (n<144) ? w_off[(size_t)k*144 + n] : (n<216 ? w_mask[(size_t)k*72 + (n-144)] : 0.f);
    w_omT[(size_t)n*256 + k] = __float2bfloat16(v);
    if (k==0) bias_om[n] = (n<144) ? b_off[n] : (n<216 ? b_mask[n-144] : 0.f);
  } else if (b < 546){
    int gid = (b-416)*8 + (threadIdx.x>>5);
    if (gid >= 1040) return;
    int n = gid/260; int ci = gid - n*260;
    int r, c;
    if (ci < 66){ r = 0; c = ci; }
    else if (ci < 132){ r = 65; c = ci-66; }
    else { int q = ci-132; r = 1 + (q>>1); c = (q&1) ? 65 : 0; }
    uint4* p = (uint4*)(R3 + ((size_t)((n*66+r)*66+c))*256) + (threadIdx.x&31);
    *p = make_uint4(0,0,0,0);
  } else if (b == 546){
    stats[threadIdx.x] = 0.f;
    stats[256+threadIdx.x] = 0.f;
    stats[512+threadIdx.x] = 0.f;
  } else {
    // NCHW fp32 -> NHWC bf16 transpose, 32x32 tile
    __shared__ float tile[32][33];
    int t = b - 547;                 // 0..4095
    int n = t >> 10;
    int c0 = ((t >> 7) & 7) * 32;
    int hw0 = (t & 127) * 32;
    int tx = threadIdx.x & 31, ty = threadIdx.x >> 5;
    #pragma unroll
    for (int ii=0; ii<4; ii++){
      int ci = ty + ii*8;
      tile[ci][tx] = x[(size_t)(n*256 + c0+ci)*4096 + hw0 + tx];
    }
    __syncthreads();
    #pragma unroll
    for (int ii=0; ii<4; ii++){
      int hwi = ty + ii*8;
      xs[((size_t)n*4096 + hw0+hwi)*256 + c0 + tx] = __float2bfloat16(tile[tx][hwi]);
    }
  }
}

// ---------------- MFMA GEMM / implicit conv, 64-row tiles, 3-buf counted-vmcnt pipeline ----------------
// AMODE 0: A=[M][KTOT] bf16. AMODE 1: A=(4,66,66,256) padded bf16, implicit 3x3, stride STRIDE.
// OMODE 0: bf16 [M][256]+bias. OMODE 1: bf16 padded +bias. OMODE 2: fp32 ldc=216 col<216.
// NSHIFT>0: accumulate per-(batch,group) sum/sumsq into stats.
template<int AMODE, int OMODE, int STRIDE, int KTOT, int NSHIFT>
__global__ __launch_bounds__(256) void k_mm(
    const __hip_bfloat16* __restrict__ A, const __hip_bfloat16* __restrict__ Bt,
    const float* __restrict__ bias, float* __restrict__ OF, __hip_bfloat16* __restrict__ OH,
    float* __restrict__ stats)
{
  constexpr int AROWS = 64;
  constexpr int MI = AROWS/32;            // 2
  constexpr int WROWS = AROWS/2;          // 32
  constexpr int JA = AROWS*128/4096;      // 2
  constexpr int BUFSZ = AROWS*128 + 16384;   // 24576
  __shared__ uint4 lds4[3*BUFSZ/16];          // 72 KB, 3 buffers
  char* ldsc = (char*)lds4;
  const int tid = threadIdx.x;
  const int lane = tid & 63;
  const int wv = tid >> 6;
  const int wr = wv >> 1, wc = wv & 1;

  // XCD-chunked bijective swizzle (nwg % 8 == 0 for all launches)
  int id = blockIdx.y * gridDim.x + blockIdx.x;
  int cpx = (gridDim.x * gridDim.y) >> 3;
  int sw = (id & 7) * cpx + (id >> 3);
  const int m0 = (sw >> 1) * AROWS, n0 = (sw & 1) * 128;

  const int swz_s = ((tid >> 3) & 7) << 4;
  const int cby = ((tid & 7) << 4) ^ swz_s;
  const int kl = cby >> 1;
  int aoff[JA], boff[4];
  #pragma unroll
  for (int j=0;j<JA;j++){
    int row = j*32 + (tid>>3);
    if (AMODE==0){
      aoff[j] = (m0 + row) * KTOT + kl;
    } else {
      int m = m0 + row;
      int n, ho, wo;
      if (STRIDE==1){ n = m>>12; ho = (m>>6)&63; wo = m&63; }
      else          { n = m>>10; ho = (m>>5)&31; wo = m&31; }
      aoff[j] = ((n*66 + ho*STRIDE)*66 + wo*STRIDE)*256 + kl;
    }
  }
  #pragma unroll
  for (int j=0;j<4;j++) boff[j] = (n0 + j*32 + (tid>>3)) * KTOT + kl;
  char* ldsst = ldsc + wv*1024;

  const int fr = lane & 15;
  const int kb = (lane >> 4) << 4;
  const int swz_r = (fr & 7) << 4;
  int aRow[MI], bRow[4];
  #pragma unroll
  for (int i=0;i<MI;i++) aRow[i] = (wr*WROWS + i*16 + fr) * 128;
  #pragma unroll
  for (int i=0;i<4;i++)  bRow[i] = AROWS*128 + (wc*64 + i*16 + fr) * 128;
  int cb[2];
  cb[0] = kb ^ swz_r;
  cb[1] = (64 | kb) ^ swz_r;

  // bias loads FIRST so the vmcnt FIFO below counts only stage loads after them
  float bn[4];
  #pragma unroll
  for (int ni=0;ni<4;ni++) bn[ni] = bias[n0 + wc*64 + ni*16 + fr];

  f32x4 acc[MI][4];
  #pragma unroll
  for (int mi=0;mi<MI;mi++)
    #pragma unroll
    for (int ni=0;ni<4;ni++)
      acc[mi][ni] = (f32x4){0.f,0.f,0.f,0.f};

  auto STAGE = [&](int buf, int t){
    const int k0 = t*64;
    int astep;
    if (AMODE==1){
      int tap = k0 >> 8;
      int kh = (tap>=6) ? 2 : (tap>=3 ? 1 : 0);
      int kw = tap - kh*3;
      astep = (kh*66 + kw)*256 + (k0 & 255);
    } else astep = k0;
    char* db = ldsst + buf*BUFSZ;
    #pragma unroll
    for (int j=0;j<JA;j++) gload16(A + aoff[j] + astep, db + j*4096);
    #pragma unroll
    for (int j=0;j<4;j++)  gload16(Bt + boff[j] + k0, db + AROWS*128 + j*4096);
  };

  constexpr int NT = KTOT / 64;             // >= 4 for all instantiations
  STAGE(0, 0);
  STAGE(1, 1);
  // stage(0) complete (6 newest in flight = stage(1)); bias also drained
  asm volatile("s_waitcnt vmcnt(6)" ::: "memory");
  __builtin_amdgcn_s_barrier();
  __builtin_amdgcn_sched_barrier(0);
  for (int t=0; t<NT; ++t){
    if (t+2 < NT) STAGE((t+2)%3, t+2);
    char* cbase = ldsc + (t%3)*BUFSZ;
    __builtin_amdgcn_s_setprio(1);
    #pragma unroll
    for (int kk=0; kk<2; kk++){
      bf16x8 av[MI], bv[4];
      #pragma unroll
      for (int i=0;i<MI;i++) av[i] = *(const bf16x8*)(cbase + aRow[i] + cb[kk]);
      #pragma unroll
      for (int i=0;i<4;i++)  bv[i] = *(const bf16x8*)(cbase + bRow[i] + cb[kk]);
      #pragma unroll
      for (int mi=0;mi<MI;mi++)
        #pragma unroll
        for (int ni=0;ni<4;ni++)
          acc[mi][ni] = __builtin_amdgcn_mfma_f32_16x16x32_bf16(av[mi], bv[ni], acc[mi][ni], 0,0,0);
    }
    __builtin_amdgcn_s_setprio(0);
    if (t < NT-1){
      if (t+2 < NT) asm volatile("s_waitcnt vmcnt(6)" ::: "memory");  // stage(t+1) done; stage(t+2) in flight
      else          asm volatile("s_waitcnt vmcnt(0)" ::: "memory");  // drain tail
      __builtin_amdgcn_s_barrier();
      __builtin_amdgcn_sched_barrier(0);
    }
  }

  float sni[4] = {0.f,0.f,0.f,0.f};
  float qni[4] = {0.f,0.f,0.f,0.f};
  #pragma unroll
  for (int mi=0;mi<MI;mi++){
    #pragma unroll
    for (int r=0;r<4;r++){
      int gr = m0 + wr*WROWS + mi*16 + (lane>>4)*4 + r;
      #pragma unroll
      for (int ni=0;ni<4;ni++){
        int gc = n0 + wc*64 + ni*16 + fr;
        float v = acc[mi][ni][r] + bn[ni];
        if (NSHIFT){ sni[ni] += v; qni[ni] += v*v; }
        if (OMODE==0){
          OH[(size_t)gr*256 + gc] = __float2bfloat16(v);
        } else if (OMODE==1){
          int n = gr>>12, h = (gr>>6)&63, w = gr&63;
          OH[((size_t)((n*66)+(h+1))*66 + (w+1))*256 + gc] = __float2bfloat16(v);
        } else {
          if (gc < 216) OF[(size_t)gr*216 + gc] = v;
        }
      }
    }
  }
  if (NSHIFT){
    #pragma unroll
    for (int ni=0;ni<4;ni++){
      #pragma unroll
      for (int msk=16; msk<64; msk<<=1){
        sni[ni] += __shfl_xor(sni[ni], msk);
        qni[ni] += __shfl_xor(qni[ni], msk);
      }
      #pragma unroll
      for (int msk=1; msk<8; msk<<=1){
        sni[ni] += __shfl_xor(sni[ni], msk);
        qni[ni] += __shfl_xor(qni[ni], msk);
      }
    }
    __syncthreads();                 // all waves out of the K-loop before LDS reuse (buf0 aliases ls)
    float* ls = (float*)ldsc;
    if (tid < 32) ls[tid] = 0.f;
    __syncthreads();
    if ((lane & 7) == 0 && (lane & 48) == 0){
      int oct = (lane>>3) & 1;
      #pragma unroll
      for (int ni=0;ni<4;ni++){
        int idx = wc*8 + ni*2 + oct;
        atomicAdd(&ls[idx], sni[ni]);
        atomicAdd(&ls[16+idx], qni[ni]);
      }
    }
    __syncthreads();
    if (tid < 16){
      int gg = (m0>>NSHIFT)*32 + (n0>>3) + tid;
      atomicAdd(&stats[gg*2+0], ls[tid]);
      atomicAdd(&stats[gg*2+1], ls[16+tid]);
    }
  }
}

// ---------------- depthwise conv 3x3 + LayerNorm + GELU, 8ch/thread, 16B loads ----------------
__global__ __launch_bounds__(256) void k_dwln(
    const __hip_bfloat16* __restrict__ xs, const float* __restrict__ dw_w, const float* __restrict__ dw_b,
    const float* __restrict__ ln_g, const float* __restrict__ ln_b, __hip_bfloat16* __restrict__ t)
{
  __shared__ float lw[9*256];
  __shared__ float lb[256], lg[256], lbt[256];
  int tid = threadIdx.x;
  #pragma unroll
  for (int p=0;p<9;p++) lw[p*256+tid] = dw_w[p*256+tid];
  lb[tid] = dw_b[tid]; lg[tid] = ln_g[tid]; lbt[tid] = ln_b[tid];
  __syncthreads();
  int posl = tid>>5, cg = tid&31, c0 = cg*8;
  int pos = blockIdx.x*8 + posl;
  int nb = pos>>12, h = (pos>>6)&63, w = pos&63;
  float v[8];
  #pragma unroll
  for (int k=0;k<8;k++) v[k] = lb[c0+k];
  #pragma unroll
  for (int kh=0;kh<3;kh++){
    int hin = h+kh-1;
    if (hin<0||hin>=64) continue;
    #pragma unroll
    for (int kw=0;kw<3;kw++){
      int win = w+kw-1;
      if (win<0||win>=64) continue;
      const unsigned short* xr = (const unsigned short*)xs + ((size_t)((nb*64+hin)*64+win))*256 + c0;
      uint4 u = *(const uint4*)xr;
      const float* wr = &lw[(kh*3+kw)*256 + c0];
      v[0] += blo(u.x)*wr[0]; v[1] += bhi(u.x)*wr[1];
      v[2] += blo(u.y)*wr[2]; v[3] += bhi(u.y)*wr[3];
      v[4] += blo(u.z)*wr[4]; v[5] += bhi(u.z)*wr[5];
      v[6] += blo(u.w)*wr[6]; v[7] += bhi(u.w)*wr[7];
    }
  }
  float s=0.f, s2=0.f;
  #pragma unroll
  for (int k=0;k<8;k++){ s += v[k]; s2 += v[k]*v[k]; }
  #pragma unroll
  for (int m=1;m<32;m<<=1){ s += __shfl_xor(s,m); s2 += __shfl_xor(s2,m); }
  float mu = s*(1.f/256.f);
  float var = s2*(1.f/256.f) - mu*mu;
  float rstd = rsqrtf(var + 1e-5f);
  float ge[8];
  #pragma unroll
  for (int k=0;k<8;k++){
    float xn = (v[k]-mu)*rstd*lg[c0+k] + lbt[c0+k];
    ge[k] = 0.5f*xn*(1.f + erff(xn*0.70710678118654752f));
  }
  uint4 o;
  o.x = pk2(ge[0],ge[1]); o.y = pk2(ge[2],ge[3]);
  o.z = pk2(ge[4],ge[5]); o.w = pk2(ge[6],ge[7]);
  *(uint4*)((unsigned short*)t + (size_t)pos*256 + c0) = o;
}

// ---------------- DCNv3 sampling: 8ch/lane, 4 lanes/group, fused softmax ----------------
__global__ __launch_bounds__(256) void k_sample(
    const __hip_bfloat16* __restrict__ xp, const float* __restrict__ D, __hip_bfloat16* __restrict__ y)
{
  int tid = threadIdx.x;
  int pp = tid>>5;
  int g = (tid>>2)&7, li = tid&3;
  int pos = blockIdx.x*8 + pp;
  int nb = pos >> 12, h = (pos >> 6) & 63, w = pos & 63;
  const float* Dp = D + (size_t)pos*216;
  const float* offp = Dp + g*18;
  const float* mskp = Dp + 144 + g*9;
  float mr[9];
  #pragma unroll
  for (int p=0;p<9;p++) mr[p] = mskp[p];
  float mx = mr[0];
  #pragma unroll
  for (int p=1;p<9;p++) mx = fmaxf(mx, mr[p]);
  float ssum = 0.f;
  #pragma unroll
  for (int p=0;p<9;p++){ mr[p] = __expf(mr[p]-mx); ssum += mr[p]; }
  float rinv = 1.f/ssum;
  const unsigned short* img = (const unsigned short*)xp + (size_t)nb*4356*256 + g*32 + li*8;
  float a0=0,a1=0,a2=0,a3=0,a4=0,a5=0,a6=0,a7=0;
  #pragma unroll
  for (int p=0;p<9;p++){
    int di = p/3 - 1, dj = p%3 - 1;
    float2 off = *(const float2*)(offp + p*2);
    float px = (float)(w + 1 + di) + off.x;
    float py = (float)(h + 1 + dj) + off.y;
    float x0f = floorf(px), y0f = floorf(py);
    float wx1 = px - x0f, wy1 = py - y0f;
    float wx0 = 1.f - wx1, wy0 = 1.f - wy1;
    int x0 = (int)x0f, y0 = (int)y0f;
    float s0=0,s1=0,s2=0,s3=0,s4=0,s5=0,s6=0,s7=0;
    #pragma unroll
    for (int cy=0;cy<2;cy++){
      int yi = y0+cy;
      if (yi<0||yi>=66) continue;
      float wy = cy ? wy1 : wy0;
      #pragma unroll
      for (int cx=0;cx<2;cx++){
        int xi = x0+cx;
        if (xi<0||xi>=66) continue;
        float wq = (cx ? wx1 : wx0)*wy;
        uint4 u = *(const uint4*)(img + (size_t)(yi*66+xi)*256);
        s0 += blo(u.x)*wq; s1 += bhi(u.x)*wq;
        s2 += blo(u.y)*wq; s3 += bhi(u.y)*wq;
        s4 += blo(u.z)*wq; s5 += bhi(u.z)*wq;
        s6 += blo(u.w)*wq; s7 += bhi(u.w)*wq;
      }
    }
    float mp = mr[p]*rinv;
    a0 += s0*mp; a1 += s1*mp; a2 += s2*mp; a3 += s3*mp;
    a4 += s4*mp; a5 += s5*mp; a6 += s6*mp; a7 += s7*mp;
  }
  uint4 o;
  o.x = pk2(a0,a1); o.y = pk2(a2,a3); o.z = pk2(a4,a5); o.w = pk2(a6,a7);
  *(uint4*)((unsigned short*)y + (size_t)pos*256 + g*32 + li*8) = o;
}

// ---------------- GN apply + SiLU -> padded bf16 (+border), 8ch/thread, bf16 in ----------------
__global__ __launch_bounds__(256) void k_gnapply(
    const __hip_bfloat16* __restrict__ X, const float* __restrict__ stats,
    const float* __restrict__ gamma, const float* __restrict__ beta,
    __hip_bfloat16* __restrict__ OH, int nmain)
{
  int b = blockIdx.x;
  int tid = threadIdx.x;
  if (b >= nmain){
    int gid = (b - nmain)*8 + (tid>>5);
    if (gid >= 1040) return;
    int n = gid/260; int ci = gid - n*260;
    int r, c;
    if (ci < 66){ r = 0; c = ci; }
    else if (ci < 132){ r = 65; c = ci-66; }
    else { int q = ci-132; r = 1 + (q>>1); c = (q&1) ? 65 : 0; }
    uint4* p = (uint4*)(OH + ((size_t)((n*66+r)*66+c))*256) + (tid&31);
    *p = make_uint4(0,0,0,0);
    return;
  }
  int row = b*8 + (tid>>5);
  int grp = tid & 31;
  int c0 = grp*8;
  int nb = row >> 12;
  float S  = stats[(nb*32+grp)*2+0];
  float S2 = stats[(nb*32+grp)*2+1];
  const float inv = 1.f/32768.f;
  float mu = S*inv;
  float rs = rsqrtf(S2*inv - mu*mu + 1e-5f);
  float4 g0 = *(const float4*)(gamma + c0), g1 = *(const float4*)(gamma + c0 + 4);
  float4 bt0 = *(const float4*)(beta + c0), bt1 = *(const float4*)(beta + c0 + 4);
  uint4 u = *(const uint4*)((const unsigned short*)X + (size_t)row*256 + c0);
  float v[8] = { blo(u.x), bhi(u.x), blo(u.y), bhi(u.y), blo(u.z), bhi(u.z), blo(u.w), bhi(u.w) };
  float gm[8] = { g0.x,g0.y,g0.z,g0.w,g1.x,g1.y,g1.z,g1.w };
  float bb[8] = { bt0.x,bt0.y,bt0.z,bt0.w,bt1.x,bt1.y,bt1.z,bt1.w };
  #pragma unroll
  for (int k=0;k<8;k++){
    float t = (v[k]-mu)*rs*gm[k] + bb[k];
    v[k] = t / (1.f + expf(-t));
  }
  int h = (row>>6)&63, w = row&63;
  uint4 o;
  o.x = pk2(v[0],v[1]); o.y = pk2(v[2],v[3]); o.z = pk2(v[4],v[5]); o.w = pk2(v[6],v[7]);
  *(uint4*)((unsigned short*)OH + ((size_t)((nb*66)+(h+1))*66 + (w+1))*256 + c0) = o;
}

// ---------------- GN3 apply -> fp32 NCHW out, LDS transpose for coalesced write ----------------
__global__ __launch_bounds__(256) void k_gnout(
    const __hip_bfloat16* __restrict__ X, const float* __restrict__ stats,
    const float* __restrict__ gamma, const float* __restrict__ beta, float* __restrict__ out)
{
  __shared__ float val[8][1024];
  int nb = blockIdx.x >> 5, cg = blockIdx.x & 31;
  int c0 = cg*8;
  float S  = stats[(nb*32+cg)*2+0];
  float S2 = stats[(nb*32+cg)*2+1];
  const float inv = 1.f/8192.f;
  float mu = S*inv;
  float rs = rsqrtf(S2*inv - mu*mu + 1e-5f);
  float4 g0 = *(const float4*)(gamma + c0), g1 = *(const float4*)(gamma + c0 + 4);
  float4 bt0 = *(const float4*)(beta + c0), bt1 = *(const float4*)(beta + c0 + 4);
  float gm[8] = { g0.x,g0.y,g0.z,g0.w,g1.x,g1.y,g1.z,g1.w };
  float bb[8] = { bt0.x,bt0.y,bt0.z,bt0.w,bt1.x,bt1.y,bt1.z,bt1.w };
  #pragma unroll
  for (int k=0;k<4;k++){
    int pos = k*256 + threadIdx.x;
    uint4 u = *(const uint4*)((const unsigned short*)X + ((size_t)(nb*1024+pos))*256 + c0);
    float v[8] = { blo(u.x), bhi(u.x), blo(u.y), bhi(u.y), blo(u.z), bhi(u.z), blo(u.w), bhi(u.w) };
    #pragma unroll
    for (int q=0;q<8;q++) val[q][pos] = (v[q]-mu)*rs*gm[q] + bb[q];
  }
  __syncthreads();
  int ch = threadIdx.x>>5, pl = threadIdx.x&31;
  float* orow = out + (((size_t)(nb*256 + c0 + ch))<<10);
  #pragma unroll
  for (int j=0;j<32;j++) orow[pl + j*32] = val[ch][pl + j*32];
}

extern "C" void kernel_launch(void* const* d_in, const int* in_sizes, int n_in,
                              void* d_out, int out_size, void* d_ws, size_t ws_size,
                              hipStream_t stream) {
  const float* x      = (const float*)d_in[0];
  const float* w_in   = (const float*)d_in[1];
  const float* b_in   = (const float*)d_in[2];
  const float* dw_w   = (const float*)d_in[3];
  const float* dw_b   = (const float*)d_in[4];
  const float* ln_g   = (const float*)d_in[5];
  const float* ln_b   = (const float*)d_in[6];
  const float* w_off  = (const float*)d_in[7];
  const float* b_off  = (const float*)d_in[8];
  const float* w_mask = (const float*)d_in[9];
  const float* b_mask = (const float*)d_in[10];
  const float* w_out  = (const float*)d_in[11];
  const float* b_out  = (const float*)d_in[12];
  const float* gn1_g  = (const float*)d_in[13];
  const float* gn1_b  = (const float*)d_in[14];
  const float* conv1_w= (const float*)d_in[15];
  const float* conv1_b= (const float*)d_in[16];
  const float* gn2_g  = (const float*)d_in[17];
  const float* gn2_b  = (const float*)d_in[18];
  const float* down_w = (const float*)d_in[19];
  const float* down_b = (const float*)d_in[20];
  const float* gn3_g  = (const float*)d_in[21];
  const float* gn3_b  = (const float*)d_in[22];
  float* out = (float*)d_out;

  char* wsb = (char*)d_ws;
  __hip_bfloat16* R0h = (__hip_bfloat16*)wsb;             // 8 MB bf16 (y2 / down-out)
  float* R1f = (float*)(wsb + 16777216);                  // 14.2 MB fp32 (offmask) / bf16 conv1-out
  __hip_bfloat16* R1h = (__hip_bfloat16*)(wsb + 16777216);
  __hip_bfloat16* R2 = (__hip_bfloat16*)(wsb + 33554432); // 8 MB bf16 (xs -> agg)
  __hip_bfloat16* R3 = (__hip_bfloat16*)(wsb + 41943040); // 8.92 MB bf16 (xp -> gn2pad)
  __hip_bfloat16* R4 = (__hip_bfloat16*)(wsb + 50864128); // 8.92 MB bf16 (t -> gn1pad)
  char* R5 = wsb + 59785216;
  __hip_bfloat16* w_inT  = (__hip_bfloat16*)R5;
  __hip_bfloat16* w_outT = (__hip_bfloat16*)(R5 + 131072);
  __hip_bfloat16* w_omT  = (__hip_bfloat16*)(R5 + 262144);
  __hip_bfloat16* c1T    = (__hip_bfloat16*)(R5 + 393216);
  __hip_bfloat16* dnT    = (__hip_bfloat16*)(R5 + 1572864);
  float* bias_om         = (float*)(R5 + 2752512);
  float* stats           = (float*)(R5 + 2753536);        // 768 floats: GN1|GN2|GN3

  // 0. fused prep (weights, offmask, R3 border, stats zero, NCHW->NHWC)
  k_prep<<<4643, 256, 0, stream>>>(x, w_in, w_out, conv1_w, down_w, w_off, w_mask, b_off, b_mask,
                                   w_inT, w_outT, c1T, dnT, w_omT, bias_om, stats, R3, R2);
  // 1. input_proj -> padded bf16 xp (R3)
  k_mm<0,1,1,256,0><<<dim3(256,2), 256, 0, stream>>>(R2, w_inT, b_in, nullptr, R3, nullptr);
  // 2. depthwise conv + LN + GELU -> t (R4 flat)
  k_dwln<<<2048, 256, 0, stream>>>(R2, dw_w, dw_b, ln_g, ln_b, R4);
  // 3. fused offset+mask GEMM -> R1 fp32
  k_mm<0,2,1,256,0><<<dim3(256,2), 256, 0, stream>>>(R4, w_omT, bias_om, R1f, nullptr, nullptr);
  // 4. sample -> agg (R2)
  k_sample<<<2048, 256, 0, stream>>>(R3, R1f, R2);
  // 5. output_proj -> R0 bf16 + GN1 stats
  k_mm<0,0,1,256,12><<<dim3(256,2), 256, 0, stream>>>(R2, w_outT, b_out, nullptr, R0h, stats);
  // 6. GN1 + SiLU -> padded bf16 (R4) + border
  k_gnapply<<<2048+130, 256, 0, stream>>>(R0h, stats, gn1_g, gn1_b, R4, 2048);
  // 7. conv1 -> R1 bf16 + GN2 stats
  k_mm<1,0,1,2304,12><<<dim3(256,2), 256, 0, stream>>>(R4, c1T, conv1_b, nullptr, R1h, stats+256);
  // 8. GN2 + SiLU -> padded bf16 (R3) + border
  k_gnapply<<<2048+130, 256, 0, stream>>>(R1h, stats+256, gn2_g, gn2_b, R3, 2048);
  // 9. down conv stride 2 -> R0 bf16 + GN3 stats
  k_mm<1,0,2,2304,10><<<dim3(64,2), 256, 0, stream>>>(R3, dnT, down_b, nullptr, R0h, stats+512);
  // 10. GN3 -> out NCHW fp32 (coalesced via LDS transpose)
  k_gnout<<<128, 256, 0, stream>>>(R0h, stats+512, gn3_g, gn3_b, out);
}